// Round 1
// baseline (1388.374 us; speedup 1.0000x reference)
//
#include <hip/hip_runtime.h>

#define SEQ 4224

__device__ __forceinline__ float prelu_f(float x, float a){ return x > 0.f ? x : a*x; }

// ---------------- spatial convs ----------------
template<int CIN, int COUT, int HW, int ACT>
__global__ __launch_bounds__(256) void conv3x3(const float* __restrict__ in, const float* __restrict__ w,
                          const float* __restrict__ bias, const float* __restrict__ alpha,
                          float* __restrict__ out) {
  int t = blockIdx.x*256 + threadIdx.x;
  if (t >= COUT*HW*HW) return;
  int x = t % HW, y = (t/HW) % HW, o = t/(HW*HW);
  float acc = bias[o];
  for (int i=0;i<CIN;++i) {
    const float* ip = in + i*HW*HW;
    const float* wp = w + (o*CIN+i)*9;
    #pragma unroll
    for (int ky=0;ky<3;++ky){
      int yy = y+ky-1;
      if ((unsigned)yy >= (unsigned)HW) continue;
      #pragma unroll
      for (int kx=0;kx<3;++kx){
        int xx = x+kx-1;
        if ((unsigned)xx >= (unsigned)HW) continue;
        acc += ip[yy*HW+xx]*wp[ky*3+kx];
      }
    }
  }
  if (ACT) acc = prelu_f(acc, alpha[0]);
  out[t] = acc;
}

__global__ __launch_bounds__(256) void conv_s3(const float* __restrict__ in, const float* __restrict__ w,
                        const float* __restrict__ bias, float* __restrict__ out) {
  int t = blockIdx.x*256+threadIdx.x; // 24*16*16
  if (t>=6144) return;
  int x=t&15, y=(t>>4)&15, o=t>>8;
  float acc = bias[o];
  for (int i=0;i<96;++i){
    const float* ip = in + i*2304 + y*3*48 + x*3;
    const float* wp = w + (o*96+i)*9;
    #pragma unroll
    for (int ky=0;ky<3;++ky)
      #pragma unroll
      for (int kx=0;kx<3;++kx)
        acc += ip[ky*48+kx]*wp[ky*3+kx];
  }
  out[t]=acc;
}

// ---------------- gather + concat entity features ----------------
__global__ __launch_bounds__(256) void gather_concat(const float* __restrict__ sm,
  const float* __restrict__ p0f, const float* __restrict__ p0u,
  const float* __restrict__ p1f, const float* __restrict__ p1u,
  const int* __restrict__ p0fp, const int* __restrict__ p0up,
  const int* __restrict__ p1fp, const int* __restrict__ p1up,
  float* __restrict__ F0, float* __restrict__ U0, float* __restrict__ F1, float* __restrict__ U1)
{
  int e = blockIdx.x*256+threadIdx.x;
  if (e>=SEQ) return;
  const float* feat; const int* pos; float* dst; int nf, n;
  if (e<64){ n=e; feat=p0f+n*7; pos=p0fp; dst=F0+n*31; nf=7; }
  else if (e<2112){ n=e-64; feat=p0u+n*14; pos=p0up; dst=U0+(size_t)n*38; nf=14; }
  else if (e<2176){ n=e-2112; feat=p1f+n*7; pos=p1fp; dst=F1+n*31; nf=7; }
  else { n=e-2176; feat=p1u+n*14; pos=p1up; dst=U1+(size_t)n*38; nf=14; }
  for (int c=0;c<nf;++c) dst[c]=feat[c];
  int px = pos[2*n], py = pos[2*n+1];
  const float* s = sm + px*16 + py;
  for (int c=0;c<24;++c) dst[nf+c] = s[c*256];
}

// ---------------- value-map build ----------------
__global__ __launch_bounds__(256) void vmap_init(const float* __restrict__ sm, float* __restrict__ vmap){
  int t = blockIdx.x*256+threadIdx.x;
  if (t>=66*256) return;
  int c = t>>8;
  vmap[t] = (c<42)? 0.f : sm[t - 42*256];
}

__global__ __launch_bounds__(256) void vmap_scatter(
  const float* __restrict__ p0f, const float* __restrict__ p0u,
  const float* __restrict__ p1f, const float* __restrict__ p1u,
  const int* __restrict__ p0fp, const int* __restrict__ p0up,
  const int* __restrict__ p1fp, const int* __restrict__ p1up,
  float* __restrict__ vmap)
{
  int e = blockIdx.x*256+threadIdx.x;
  if (e>=SEQ) return;
  const float* feat; const int* pos; int n, ch0, C;
  if (e<2048){ n=e; feat=p1u+n*14; pos=p1up; ch0=0; C=14; }
  else if (e<2112){ n=e-2048; feat=p1f+n*7; pos=p1fp; ch0=14; C=7; }
  else if (e<4160){ n=e-2112; feat=p0u+n*14; pos=p0up; ch0=21; C=14; }
  else { n=e-4160; feat=p0f+n*7; pos=p0fp; ch0=35; C=7; }
  int off = pos[2*n]*16 + pos[2*n+1];
  for (int c=0;c<C;++c) atomicAdd(&vmap[(ch0+c)*256 + off], feat[c]);
}

// ---------------- QKV projection (enc + ext unified) ----------------
__global__ __launch_bounds__(256) void qkv_proj(const float* __restrict__ x0, const float* __restrict__ x1,
    const float* __restrict__ x2, const float* __restrict__ x3, int ind_f, int ind_u,
    const float* __restrict__ fw, const float* __restrict__ fb,
    const float* __restrict__ uw, const float* __restrict__ ub,
    float* __restrict__ Q, float* __restrict__ K, float* __restrict__ V){
  __shared__ float Xs[64*38];
  __shared__ float Ws[32*39];
  __shared__ float Bs[32];
  int blk = blockIdx.x;
  int chunk = blk % 66;
  int hm = blk / 66;       // 0..5 = m*2+h
  int m = hm >> 1, h = hm & 1;
  const float* xb; int ind, isfac, pl;
  if (chunk==0){ xb=x0; ind=ind_f; isfac=1; pl=0; }
  else if (chunk<=32){ xb=x1 + (size_t)(chunk-1)*64*ind_u; ind=ind_u; isfac=0; pl=0; }
  else if (chunk==33){ xb=x2; ind=ind_f; isfac=1; pl=1; }
  else { xb=x3 + (size_t)(chunk-34)*64*ind_u; ind=ind_u; isfac=0; pl=1; }
  int b0 = h*6 + pl*3 + m;
  const float* w = (isfac? fw:uw) + (size_t)b0*32*ind;
  const float* bias = (isfac? fb:ub) + b0*32;
  int tid = threadIdx.x;
  for (int idx=tid; idx<64*ind; idx+=256) Xs[idx]=xb[idx];
  for (int idx=tid; idx<32*ind; idx+=256){ int oo=idx/ind, dd=idx-oo*ind; Ws[oo*39+dd]=w[idx]; }
  if (tid<32) Bs[tid]=bias[tid];
  __syncthreads();
  int o = tid&31, r0 = tid>>5;
  const float* xr[8];
  #pragma unroll
  for (int j=0;j<8;++j) xr[j] = &Xs[(r0+8*j)*ind];
  float acc[8];
  #pragma unroll
  for (int j=0;j<8;++j) acc[j]=Bs[o];
  for (int d=0; d<ind; ++d){
    float wv = Ws[o*39+d];
    #pragma unroll
    for (int j=0;j<8;++j) acc[j] += xr[j][d]*wv;
  }
  float* base = (m==0? Q : (m==1? K : V)) + ((size_t)h*SEQ + chunk*64)*32 + o;
  #pragma unroll
  for (int j=0;j<8;++j) base[(r0+8*j)*32] = acc[j];
}

// ---------------- flash attention (fp32, Qb=32, Kb=64, K-split=2) ----------------
__global__ __launch_bounds__(256) void flash_attn(const float* __restrict__ Qg, const float* __restrict__ Kg,
    const float* __restrict__ Vg, float* __restrict__ Hpart, float* __restrict__ aux){
  __shared__ float Qs[32][32];
  __shared__ float Ks[64][36];
  __shared__ float Vs[64][36];
  __shared__ float Ps[32][68];
  int qb = blockIdx.x, h = blockIdx.y, ks = blockIdx.z;
  const float* Qh = Qg + (size_t)h*SEQ*32;
  const float* Kh = Kg + (size_t)h*SEQ*32;
  const float* Vh = Vg + (size_t)h*SEQ*32;
  int tid = threadIdx.x;
  int q = tid>>3, kg = tid&7, d0 = kg*4;
  {
    float4 qv = *(const float4*)(Qh + (qb*32+q)*32 + d0);
    *(float4*)&Qs[q][d0] = qv;
  }
  float acc0=0.f,acc1=0.f,acc2=0.f,acc3=0.f;
  float mrow=-1e30f, lrow=0.f;
  const float scale = 0.17677669529663687f; // 1/sqrt(32)
  int lr = tid>>2, lc = (tid&3)*8;
  for (int it=0; it<33; ++it){
    int kt = ks*33 + it;
    __syncthreads();
    {
      const float* kp = Kh + (size_t)(kt*64+lr)*32 + lc;
      float4 a0 = *(const float4*)kp;
      float4 a1 = *(const float4*)(kp+4);
      *(float4*)&Ks[lr][lc] = a0;
      *(float4*)&Ks[lr][lc+4] = a1;
      const float* vp = Vh + (size_t)(kt*64+lr)*32 + lc;
      float4 b0 = *(const float4*)vp;
      float4 b1 = *(const float4*)(vp+4);
      *(float4*)&Vs[lr][lc] = b0;
      *(float4*)&Vs[lr][lc+4] = b1;
    }
    __syncthreads();
    float sv[8];
    #pragma unroll
    for (int j=0;j<8;++j) sv[j]=0.f;
    #pragma unroll
    for (int dd=0;dd<32;dd+=4){
      float4 qv = *(const float4*)&Qs[q][dd];
      #pragma unroll
      for (int j=0;j<8;++j){
        float4 kv = *(const float4*)&Ks[kg+8*j][dd];
        sv[j] += qv.x*kv.x + qv.y*kv.y + qv.z*kv.z + qv.w*kv.w;
      }
    }
    float tm=-1e30f;
    #pragma unroll
    for (int j=0;j<8;++j){ sv[j]*=scale; tm=fmaxf(tm,sv[j]); }
    tm = fmaxf(tm, __shfl_xor(tm,1));
    tm = fmaxf(tm, __shfl_xor(tm,2));
    tm = fmaxf(tm, __shfl_xor(tm,4));
    float mnew = fmaxf(mrow, tm);
    float resc = __expf(mrow-mnew);
    float ts=0.f;
    #pragma unroll
    for (int j=0;j<8;++j){ sv[j]=__expf(sv[j]-mnew); ts+=sv[j]; }
    ts += __shfl_xor(ts,1); ts += __shfl_xor(ts,2); ts += __shfl_xor(ts,4);
    lrow = lrow*resc + ts;
    mrow = mnew;
    acc0*=resc; acc1*=resc; acc2*=resc; acc3*=resc;
    #pragma unroll
    for (int j=0;j<8;++j) Ps[q][kg+8*j] = sv[j];
    // Ps row q written & read by the same 8 lanes of this wave: DS ops are
    // in-order within a wave, compiler keeps order (same array, unprovable alias)
    #pragma unroll
    for (int k=0;k<64;k+=4){
      float4 pv = *(const float4*)&Ps[q][k];
      float4 v0 = *(const float4*)&Vs[k  ][d0];
      float4 v1 = *(const float4*)&Vs[k+1][d0];
      float4 v2 = *(const float4*)&Vs[k+2][d0];
      float4 v3 = *(const float4*)&Vs[k+3][d0];
      acc0 += pv.x*v0.x + pv.y*v1.x + pv.z*v2.x + pv.w*v3.x;
      acc1 += pv.x*v0.y + pv.y*v1.y + pv.z*v2.y + pv.w*v3.y;
      acc2 += pv.x*v0.z + pv.y*v1.z + pv.z*v2.z + pv.w*v3.z;
      acc3 += pv.x*v0.w + pv.y*v1.w + pv.z*v2.w + pv.w*v3.w;
    }
  }
  float* op = Hpart + ((size_t)ks*SEQ + qb*32 + q)*64 + h*32 + d0;
  op[0]=acc0; op[1]=acc1; op[2]=acc2; op[3]=acc3;
  if (kg==0){
    float* ap = aux + ((size_t)(ks*2+h)*SEQ + qb*32 + q)*2;
    ap[0]=mrow; ap[1]=lrow;
  }
}

__global__ __launch_bounds__(256) void flash_combine(const float* __restrict__ Hpart,
    const float* __restrict__ aux, float* __restrict__ H){
  int t = blockIdx.x*256+threadIdx.x;
  if (t>=SEQ*64) return;
  int h = (t>>5)&1;
  int s = t>>6;
  const float* a0 = aux + ((size_t)(0*2+h)*SEQ + s)*2;
  const float* a1 = aux + ((size_t)(1*2+h)*SEQ + s)*2;
  float m0=a0[0], l0=a0[1], m1=a1[0], l1=a1[1];
  float ms = fmaxf(m0,m1);
  float w0 = __expf(m0-ms), w1 = __expf(m1-ms);
  float inv = 1.f/(l0*w0 + l1*w1);
  H[t] = (Hpart[t]*w0 + Hpart[SEQ*64+t]*w1)*inv;
}

// ---------------- MHA output linear (+ optional residual & LN) ----------------
__global__ __launch_bounds__(256) void outlin_enc(const float* __restrict__ H, const float* __restrict__ lw,
     const float* __restrict__ lb, float* __restrict__ seqout){
  __shared__ float Ls[32*65];
  int tid=threadIdx.x;
  for (int idx=tid; idx<2048; idx+=256){ int o=idx>>6, d=idx&63; Ls[o*65+d]=lw[idx]; }
  __syncthreads();
  int t = blockIdx.x*256+tid;
  int o = t&31; int s = t>>5;
  const float* hr = H + (size_t)s*64;
  float acc = lb[o];
  #pragma unroll
  for (int d=0;d<64;++d) acc += hr[d]*Ls[o*65+d];
  seqout[t]=acc;
}

__global__ __launch_bounds__(256) void outlin_ln(const float* __restrict__ H, const float* __restrict__ lw,
    const float* __restrict__ lb, const float* __restrict__ seqin,
    const float* __restrict__ g, const float* __restrict__ b, float* __restrict__ seqout){
  __shared__ float Ls[32*65];
  int tid=threadIdx.x;
  for (int idx=tid; idx<2048; idx+=256){ int o=idx>>6, d=idx&63; Ls[o*65+d]=lw[idx]; }
  __syncthreads();
  int t = blockIdx.x*256+tid;
  int o = t&31; int s = t>>5;
  const float* hr = H + (size_t)s*64;
  float acc = lb[o] + seqin[t];
  #pragma unroll
  for (int d=0;d<64;++d) acc += hr[d]*Ls[o*65+d];
  float sum=acc;
  #pragma unroll
  for (int off=1; off<32; off<<=1) sum += __shfl_xor(sum,off);
  float mu = sum*0.03125f;
  float dv = acc-mu;
  float vs = dv*dv;
  #pragma unroll
  for (int off=1; off<32; off<<=1) vs += __shfl_xor(vs,off);
  float rstd = rsqrtf(vs*0.03125f + 1e-5f);
  seqout[t] = dv*rstd*g[o] + b[o];
}

// ---------------- per-entity output heads ----------------
__global__ __launch_bounds__(256) void head_mlp(const float* __restrict__ seq,
  const float* __restrict__ fw1,const float* __restrict__ fb1,const float* __restrict__ fa,
  const float* __restrict__ fw2,const float* __restrict__ fb2,
  const float* __restrict__ rw1,const float* __restrict__ rb1,const float* __restrict__ ra,
  const float* __restrict__ rw2,const float* __restrict__ rb2,
  float* __restrict__ out)
{
  int e = blockIdx.x*256+threadIdx.x;
  if (e>=SEQ) return;
  const float *w1,*b1,*w2,*b2; float a; int od; float* dst;
  if (e<64){ w1=fw1;b1=fb1;a=fa[0];w2=fw2;b2=fb2;od=4; dst=out + e*4; }
  else if (e<2112){ w1=rw1;b1=rb1;a=ra[0];w2=rw2;b2=rb2;od=17; dst=out + 256 + (size_t)(e-64)*17; }
  else if (e<2176){ w1=fw1;b1=fb1;a=fa[0];w2=fw2;b2=fb2;od=4; dst=out + 35072 + (e-2112)*4; }
  else { w1=rw1;b1=rb1;a=ra[0];w2=rw2;b2=rb2;od=17; dst=out + 35328 + (size_t)(e-2176)*17; }
  float x[32];
  #pragma unroll
  for (int i=0;i<32;++i) x[i]=seq[(size_t)e*32+i];
  float hbuf[32];
  #pragma unroll
  for (int j=0;j<32;++j){
    float acc=b1[j];
    #pragma unroll
    for (int i=0;i<32;++i) acc+=w1[j*32+i]*x[i];
    hbuf[j]=prelu_f(acc,a);
  }
  for (int k=0;k<od;++k){
    float acc=b2[k];
    #pragma unroll
    for (int j=0;j<32;++j) acc+=w2[k*32+j]*hbuf[j];
    dst[k]=acc;
  }
}

// ---------------- value head convs (conv+prelu+maxpool fused) ----------------
template<int CIN, int COUT, int HIN>
__global__ __launch_bounds__(256) void vconv_pool(const float* __restrict__ in, const float* __restrict__ w,
    const float* __restrict__ bias, const float* __restrict__ alpha, float* __restrict__ out){
  const int PW = HIN/2;
  int t = blockIdx.x*256+threadIdx.x;
  if (t >= COUT*PW*PW) return;
  int px = t % PW, py = (t/PW)%PW, c = t/(PW*PW);
  float a = alpha[0], mx = -1e30f;
  for (int sy=0;sy<2;++sy) for (int sx=0;sx<2;++sx){
    int y=py*2+sy, x=px*2+sx;
    float acc = bias[c];
    for (int i=0;i<CIN;++i){
      const float* ip = in + i*HIN*HIN;
      const float* wp = w + (c*CIN+i)*9;
      #pragma unroll
      for (int ky=0;ky<3;++ky){ int yy=y+ky-1; if((unsigned)yy>=(unsigned)HIN) continue;
        #pragma unroll
        for (int kx=0;kx<3;++kx){ int xx=x+kx-1; if((unsigned)xx>=(unsigned)HIN) continue;
          acc += ip[yy*HIN+xx]*wp[ky*3+kx]; } }
    }
    acc = prelu_f(acc,a);
    mx = fmaxf(mx,acc);
  }
  out[t]=mx;
}

__global__ __launch_bounds__(256) void vfinal(const float* __restrict__ vp2, const float* __restrict__ lw,
                       const float* __restrict__ lb, float* __restrict__ outv){
  __shared__ float red[256];
  int tid=threadIdx.x;
  float s=0.f;
  for (int i=tid;i<2048;i+=256) s += vp2[i]*lw[i];
  red[tid]=s; __syncthreads();
  for (int k=128;k>0;k>>=1){ if (tid<k) red[tid]+=red[tid+k]; __syncthreads(); }
  if (tid==0) outv[0] = tanhf(red[0]+lb[0]);
}

// ---------------- host ----------------
extern "C" void kernel_launch(void* const* d_in, const int* in_sizes, int n_in,
                              void* d_out, int out_size, void* d_ws, size_t ws_size,
                              hipStream_t stream){
  (void)in_sizes; (void)n_in; (void)out_size; (void)ws_size;
  const float* board = (const float*)d_in[0];
  const float* p0f = (const float*)d_in[1];
  const float* p0u = (const float*)d_in[2];
  const float* p1f = (const float*)d_in[3];
  const float* p1u = (const float*)d_in[4];
  const float* sp_w1=(const float*)d_in[5];  const float* sp_b1=(const float*)d_in[6];  const float* sp_a1=(const float*)d_in[7];
  const float* sp_w2=(const float*)d_in[8];  const float* sp_b2=(const float*)d_in[9];  const float* sp_a2=(const float*)d_in[10];
  const float* sp_w3=(const float*)d_in[11]; const float* sp_b3=(const float*)d_in[12];
  const float* enc_fac_w=(const float*)d_in[13]; const float* enc_fac_b=(const float*)d_in[14];
  const float* enc_unit_w=(const float*)d_in[15]; const float* enc_unit_b=(const float*)d_in[16];
  const float* enc_lin_w=(const float*)d_in[17]; const float* enc_lin_b=(const float*)d_in[18];
  const float* ext_fac_w=(const float*)d_in[19]; const float* ext_fac_b=(const float*)d_in[20];
  const float* ext_unit_w=(const float*)d_in[21]; const float* ext_unit_b=(const float*)d_in[22];
  const float* ext_lin_w=(const float*)d_in[23]; const float* ext_lin_b=(const float*)d_in[24];
  const float* ext_ln_g=(const float*)d_in[25]; const float* ext_ln_b=(const float*)d_in[26];
  const float* v_w1=(const float*)d_in[27]; const float* v_b1=(const float*)d_in[28]; const float* v_a1=(const float*)d_in[29];
  const float* v_w2=(const float*)d_in[30]; const float* v_b2=(const float*)d_in[31]; const float* v_a2=(const float*)d_in[32];
  const float* v_lw=(const float*)d_in[33]; const float* v_lb=(const float*)d_in[34];
  const float* fo_w1=(const float*)d_in[35]; const float* fo_b1=(const float*)d_in[36]; const float* fo_a=(const float*)d_in[37];
  const float* fo_w2=(const float*)d_in[38]; const float* fo_b2=(const float*)d_in[39];
  const float* ro_w1=(const float*)d_in[40]; const float* ro_b1=(const float*)d_in[41]; const float* ro_a=(const float*)d_in[42];
  const float* ro_w2=(const float*)d_in[43]; const float* ro_b2=(const float*)d_in[44];
  const int* p0fp=(const int*)d_in[45]; const int* p0up=(const int*)d_in[46];
  const int* p1fp=(const int*)d_in[47]; const int* p1up=(const int*)d_in[48];
  float* out = (float*)d_out;

  float* W = (float*)d_ws;
  float* sm1 = W;                    // 48*48*48
  float* sm2 = sm1 + 110592;         // 96*48*48
  float* sm  = sm2 + 221184;         // 24*16*16
  float* F0  = sm + 6144;            // 64*31
  float* U0  = F0 + 64*31;           // 2048*38
  float* F1  = U0 + 2048*38;         // 64*31
  float* U1  = F1 + 64*31;           // 2048*38
  float* Qb  = U1 + 2048*38;         // 2*SEQ*32
  float* Kb  = Qb + 2*SEQ*32;
  float* Vb  = Kb + 2*SEQ*32;
  float* Hp  = Vb + 2*SEQ*32;        // 2*SEQ*64 (ksplit partials)
  float* aux = Hp + 2*SEQ*64;        // 2*2*SEQ*2
  float* Hh  = aux + 2*2*SEQ*2;      // SEQ*64
  float* seqA= Hh + SEQ*64;          // SEQ*32
  float* seqB= seqA + SEQ*32;        // SEQ*32
  float* vmap= seqB + SEQ*32;        // 66*256
  float* vp1 = vmap + 66*256;        // 96*64
  float* vp2 = vp1 + 96*64;          // 128*16

  // spatial path
  conv3x3<14,48,48,1><<<432,256,0,stream>>>(board, sp_w1, sp_b1, sp_a1, sm1);
  conv3x3<48,96,48,1><<<864,256,0,stream>>>(sm1, sp_w2, sp_b2, sp_a2, sm2);
  conv_s3<<<24,256,0,stream>>>(sm2, sp_w3, sp_b3, sm);
  gather_concat<<<17,256,0,stream>>>(sm, p0f,p0u,p1f,p1u, p0fp,p0up,p1fp,p1up, F0,U0,F1,U1);
  vmap_init<<<66,256,0,stream>>>(sm, vmap);
  vmap_scatter<<<17,256,0,stream>>>(p0f,p0u,p1f,p1u, p0fp,p0up,p1fp,p1up, vmap);
  // value head
  vconv_pool<66,96,16><<<24,256,0,stream>>>(vmap, v_w1, v_b1, v_a1, vp1);
  vconv_pool<96,128,8><<<8,256,0,stream>>>(vp1, v_w2, v_b2, v_a2, vp2);
  vfinal<<<1,256,0,stream>>>(vp2, v_lw, v_lb, out + 70144);

  // encoder layer
  qkv_proj<<<396,256,0,stream>>>(F0,U0,F1,U1, 31,38, enc_fac_w,enc_fac_b,enc_unit_w,enc_unit_b, Qb,Kb,Vb);
  flash_attn<<<dim3(132,2,2),256,0,stream>>>(Qb,Kb,Vb,Hp,aux);
  flash_combine<<<1056,256,0,stream>>>(Hp,aux,Hh);
  outlin_enc<<<528,256,0,stream>>>(Hh, enc_lin_w, enc_lin_b, seqA);
  // extractor layer 0
  qkv_proj<<<396,256,0,stream>>>(seqA, seqA+64*32, seqA+2112*32, seqA+2176*32, 32,32,
      ext_fac_w, ext_fac_b, ext_unit_w, ext_unit_b, Qb,Kb,Vb);
  flash_attn<<<dim3(132,2,2),256,0,stream>>>(Qb,Kb,Vb,Hp,aux);
  flash_combine<<<1056,256,0,stream>>>(Hp,aux,Hh);
  outlin_ln<<<528,256,0,stream>>>(Hh, ext_lin_w, ext_lin_b, seqA, ext_ln_g, ext_ln_b, seqB);
  // extractor layer 1
  qkv_proj<<<396,256,0,stream>>>(seqB, seqB+64*32, seqB+2112*32, seqB+2176*32, 32,32,
      ext_fac_w+12288, ext_fac_b+384, ext_unit_w+12288, ext_unit_b+384, Qb,Kb,Vb);
  flash_attn<<<dim3(132,2,2),256,0,stream>>>(Qb,Kb,Vb,Hp,aux);
  flash_combine<<<1056,256,0,stream>>>(Hp,aux,Hh);
  outlin_ln<<<528,256,0,stream>>>(Hh, ext_lin_w+2048, ext_lin_b+32, seqB, ext_ln_g+32, ext_ln_b+32, seqA);

  head_mlp<<<17,256,0,stream>>>(seqA, fo_w1,fo_b1,fo_a,fo_w2,fo_b2, ro_w1,ro_b1,ro_a,ro_w2,ro_b2, out);
}

// Round 2
// 731.320 us; speedup vs baseline: 1.8984x; 1.8984x over previous
//
#include <hip/hip_runtime.h>

#define SEQ 4224

__device__ __forceinline__ float prelu_f(float x, float a){ return x > 0.f ? x : a*x; }

// ---------------- spatial convs (weights in LDS, CPT channels/thread) ----------------
template<int CIN, int COUT, int HW, int ACT, int CPT>
__global__ __launch_bounds__(256) void conv3x3_v2(const float* __restrict__ in, const float* __restrict__ w,
                          const float* __restrict__ bias, const float* __restrict__ alpha,
                          float* __restrict__ out) {
  __shared__ float Ws[CPT*CIN*9];
  __shared__ float Bs[CPT];
  const int PXB = HW*HW/256;
  int cg = blockIdx.x / PXB, pxb = blockIdx.x % PXB;
  int tid = threadIdx.x;
  for (int idx=tid; idx<CPT*CIN*9; idx+=256) Ws[idx] = w[cg*CPT*CIN*9 + idx];
  if (tid<CPT) Bs[tid] = bias[cg*CPT+tid];
  __syncthreads();
  int p = pxb*256 + tid;
  int x = p % HW, y = p / HW;
  float a = ACT ? alpha[0] : 0.f;
  float acc[CPT];
  #pragma unroll
  for (int c=0;c<CPT;++c) acc[c]=Bs[c];
  #pragma unroll 2
  for (int i=0;i<CIN;++i){
    const float* ip = in + i*HW*HW;
    float win[9];
    #pragma unroll
    for (int ky=0;ky<3;++ky){
      int yy = y+ky-1;
      #pragma unroll
      for (int kx=0;kx<3;++kx){
        int xx = x+kx-1;
        bool ok = ((unsigned)yy < (unsigned)HW) && ((unsigned)xx < (unsigned)HW);
        win[ky*3+kx] = ok ? ip[yy*HW+xx] : 0.f;
      }
    }
    #pragma unroll
    for (int c=0;c<CPT;++c){
      const float* wp = &Ws[(c*CIN+i)*9];
      #pragma unroll
      for (int k=0;k<9;++k) acc[c] += win[k]*wp[k];
    }
  }
  #pragma unroll
  for (int c=0;c<CPT;++c){
    float v = acc[c];
    if (ACT) v = prelu_f(v, a);
    out[(cg*CPT+c)*HW*HW + p] = v;
  }
}

// stride-3 valid conv 96->24 over 48x48 -> 16x16; 2 channels per block
__global__ __launch_bounds__(256) void conv_s3_v2(const float* __restrict__ in, const float* __restrict__ w,
                        const float* __restrict__ bias, float* __restrict__ out) {
  __shared__ float Ws[2*96*9];
  int cg = blockIdx.x;   // 12 blocks
  int tid = threadIdx.x;
  for (int idx=tid; idx<1728; idx+=256) Ws[idx] = w[cg*1728 + idx];
  __syncthreads();
  int x = tid&15, y = tid>>4;
  float a0 = bias[2*cg], a1 = bias[2*cg+1];
  const float* ip0 = in + y*144 + x*3;
  #pragma unroll 4
  for (int i=0;i<96;++i){
    const float* ip = ip0 + i*2304;
    float win[9];
    #pragma unroll
    for (int ky=0;ky<3;++ky)
      #pragma unroll
      for (int kx=0;kx<3;++kx) win[ky*3+kx] = ip[ky*48+kx];
    const float* w0 = &Ws[i*9];
    const float* w1 = &Ws[864 + i*9];
    #pragma unroll
    for (int k=0;k<9;++k){ a0 += win[k]*w0[k]; a1 += win[k]*w1[k]; }
  }
  out[(2*cg)*256 + y*16 + x] = a0;
  out[(2*cg+1)*256 + y*16 + x] = a1;
}

// ---------------- gather + concat entity features ----------------
__global__ __launch_bounds__(256) void gather_concat(const float* __restrict__ sm,
  const float* __restrict__ p0f, const float* __restrict__ p0u,
  const float* __restrict__ p1f, const float* __restrict__ p1u,
  const int* __restrict__ p0fp, const int* __restrict__ p0up,
  const int* __restrict__ p1fp, const int* __restrict__ p1up,
  float* __restrict__ F0, float* __restrict__ U0, float* __restrict__ F1, float* __restrict__ U1)
{
  int e = blockIdx.x*256+threadIdx.x;
  if (e>=SEQ) return;
  const float* feat; const int* pos; float* dst; int nf, n;
  if (e<64){ n=e; feat=p0f+n*7; pos=p0fp; dst=F0+n*31; nf=7; }
  else if (e<2112){ n=e-64; feat=p0u+n*14; pos=p0up; dst=U0+(size_t)n*38; nf=14; }
  else if (e<2176){ n=e-2112; feat=p1f+n*7; pos=p1fp; dst=F1+n*31; nf=7; }
  else { n=e-2176; feat=p1u+n*14; pos=p1up; dst=U1+(size_t)n*38; nf=14; }
  for (int c=0;c<nf;++c) dst[c]=feat[c];
  int px = pos[2*n], py = pos[2*n+1];
  const float* s = sm + px*16 + py;
  #pragma unroll
  for (int c=0;c<24;++c) dst[nf+c] = s[c*256];
}

// ---------------- value-map build ----------------
__global__ __launch_bounds__(256) void vmap_init(const float* __restrict__ sm, float* __restrict__ vmap){
  int t = blockIdx.x*256+threadIdx.x;
  if (t>=66*256) return;
  int c = t>>8;
  vmap[t] = (c<42)? 0.f : sm[t - 42*256];
}

__global__ __launch_bounds__(256) void vmap_scatter(
  const float* __restrict__ p0f, const float* __restrict__ p0u,
  const float* __restrict__ p1f, const float* __restrict__ p1u,
  const int* __restrict__ p0fp, const int* __restrict__ p0up,
  const int* __restrict__ p1fp, const int* __restrict__ p1up,
  float* __restrict__ vmap)
{
  int e = blockIdx.x*256+threadIdx.x;
  if (e>=SEQ) return;
  const float* feat; const int* pos; int n, ch0, C;
  if (e<2048){ n=e; feat=p1u+n*14; pos=p1up; ch0=0; C=14; }
  else if (e<2112){ n=e-2048; feat=p1f+n*7; pos=p1fp; ch0=14; C=7; }
  else if (e<4160){ n=e-2112; feat=p0u+n*14; pos=p0up; ch0=21; C=14; }
  else { n=e-4160; feat=p0f+n*7; pos=p0fp; ch0=35; C=7; }
  int off = pos[2*n]*16 + pos[2*n+1];
  for (int c=0;c<C;++c) atomicAdd(&vmap[(ch0+c)*256 + off], feat[c]);
}

// ---------------- QKV projection (enc + ext unified) ----------------
__global__ __launch_bounds__(256) void qkv_proj(const float* __restrict__ x0, const float* __restrict__ x1,
    const float* __restrict__ x2, const float* __restrict__ x3, int ind_f, int ind_u,
    const float* __restrict__ fw, const float* __restrict__ fb,
    const float* __restrict__ uw, const float* __restrict__ ub,
    float* __restrict__ Q, float* __restrict__ K, float* __restrict__ V){
  __shared__ float Xs[64*38];
  __shared__ float Ws[32*39];
  __shared__ float Bs[32];
  int blk = blockIdx.x;
  int chunk = blk % 66;
  int hm = blk / 66;       // 0..5 = m*2+h
  int m = hm >> 1, h = hm & 1;
  const float* xb; int ind, isfac, pl;
  if (chunk==0){ xb=x0; ind=ind_f; isfac=1; pl=0; }
  else if (chunk<=32){ xb=x1 + (size_t)(chunk-1)*64*ind_u; ind=ind_u; isfac=0; pl=0; }
  else if (chunk==33){ xb=x2; ind=ind_f; isfac=1; pl=1; }
  else { xb=x3 + (size_t)(chunk-34)*64*ind_u; ind=ind_u; isfac=0; pl=1; }
  int b0 = h*6 + pl*3 + m;
  const float* w = (isfac? fw:uw) + (size_t)b0*32*ind;
  const float* bias = (isfac? fb:ub) + b0*32;
  int tid = threadIdx.x;
  for (int idx=tid; idx<64*ind; idx+=256) Xs[idx]=xb[idx];
  for (int idx=tid; idx<32*ind; idx+=256){ int oo=idx/ind, dd=idx-oo*ind; Ws[oo*39+dd]=w[idx]; }
  if (tid<32) Bs[tid]=bias[tid];
  __syncthreads();
  int o = tid&31, r0 = tid>>5;
  const float* xr[8];
  #pragma unroll
  for (int j=0;j<8;++j) xr[j] = &Xs[(r0+8*j)*ind];
  float acc[8];
  #pragma unroll
  for (int j=0;j<8;++j) acc[j]=Bs[o];
  for (int d=0; d<ind; ++d){
    float wv = Ws[o*39+d];
    #pragma unroll
    for (int j=0;j<8;++j) acc[j] += xr[j][d]*wv;
  }
  float* base = (m==0? Q : (m==1? K : V)) + ((size_t)h*SEQ + chunk*64)*32 + o;
  #pragma unroll
  for (int j=0;j<8;++j) base[(r0+8*j)*32] = acc[j];
}

// ---------------- flash attention v2 (fp32, Qb=64, Kb=64, K-split=3) ----------------
// thread (q4 in [0,16), kg/dg in [0,16)): QK owns 4 q-rows x 4 k-cols, PV owns 4 q-rows x 2 d.
__global__ __launch_bounds__(256) void flash_attn2(const float* __restrict__ Qg, const float* __restrict__ Kg,
    const float* __restrict__ Vg, float* __restrict__ Hpart, float* __restrict__ aux){
  __shared__ float Qs[64][36];
  __shared__ float Ks[64][36];
  __shared__ float Vs[64][36];
  __shared__ float Ps[64][68];
  int qb = blockIdx.x, h = blockIdx.y, ks = blockIdx.z;
  const float* Qh = Qg + (size_t)h*SEQ*32;
  const float* Kh = Kg + (size_t)h*SEQ*32;
  const float* Vh = Vg + (size_t)h*SEQ*32;
  int tid = threadIdx.x;
  int q4 = tid >> 4, kg = tid & 15;
  int d0 = kg*2;
  // stage Q tile (64x32) into LDS
  int sr = tid>>2, sc = (tid&3)*8;
  {
    const float* qp = Qh + (size_t)(qb*64 + sr)*32 + sc;
    *(float4*)&Qs[sr][sc]   = *(const float4*)qp;
    *(float4*)&Qs[sr][sc+4] = *(const float4*)(qp+4);
  }
  float mr[4], lr[4], acc[4][2];
  #pragma unroll
  for (int i=0;i<4;++i){ mr[i]=-1e30f; lr[i]=0.f; acc[i][0]=0.f; acc[i][1]=0.f; }
  const float scale = 0.17677669529663687f; // 1/sqrt(32)
  int kt0 = ks*22;
  float4 ka, kb, va, vb;
  {
    const float* kp = Kh + (size_t)(kt0*64 + sr)*32 + sc;
    ka = *(const float4*)kp; kb = *(const float4*)(kp+4);
    const float* vp = Vh + (size_t)(kt0*64 + sr)*32 + sc;
    va = *(const float4*)vp; vb = *(const float4*)(vp+4);
  }
  for (int it=0; it<22; ++it){
    *(float4*)&Ks[sr][sc]   = ka; *(float4*)&Ks[sr][sc+4] = kb;
    *(float4*)&Vs[sr][sc]   = va; *(float4*)&Vs[sr][sc+4] = vb;
    __syncthreads();
    if (it < 21){
      const float* kp = Kh + (size_t)((kt0+it+1)*64 + sr)*32 + sc;
      ka = *(const float4*)kp; kb = *(const float4*)(kp+4);
      const float* vp = Vh + (size_t)((kt0+it+1)*64 + sr)*32 + sc;
      va = *(const float4*)vp; vb = *(const float4*)(vp+4);
    }
    // ---- QK: s[i][j], i=q-row group, j=k group ----
    float sv[4][4];
    #pragma unroll
    for (int i=0;i<4;++i)
      #pragma unroll
      for (int j=0;j<4;++j) sv[i][j]=0.f;
    #pragma unroll 2
    for (int dd=0; dd<32; dd+=4){
      float4 q0 = *(const float4*)&Qs[q4   ][dd];
      float4 q1 = *(const float4*)&Qs[q4+16][dd];
      float4 q2 = *(const float4*)&Qs[q4+32][dd];
      float4 q3 = *(const float4*)&Qs[q4+48][dd];
      float4 k0 = *(const float4*)&Ks[kg   ][dd];
      float4 k1 = *(const float4*)&Ks[kg+16][dd];
      float4 k2 = *(const float4*)&Ks[kg+32][dd];
      float4 k3 = *(const float4*)&Ks[kg+48][dd];
#define DOT4(I,J,QV,KV) sv[I][J] += QV.x*KV.x + QV.y*KV.y + QV.z*KV.z + QV.w*KV.w;
      DOT4(0,0,q0,k0) DOT4(0,1,q0,k1) DOT4(0,2,q0,k2) DOT4(0,3,q0,k3)
      DOT4(1,0,q1,k0) DOT4(1,1,q1,k1) DOT4(1,2,q1,k2) DOT4(1,3,q1,k3)
      DOT4(2,0,q2,k0) DOT4(2,1,q2,k1) DOT4(2,2,q2,k2) DOT4(2,3,q2,k3)
      DOT4(3,0,q3,k0) DOT4(3,1,q3,k1) DOT4(3,2,q3,k2) DOT4(3,3,q3,k3)
#undef DOT4
    }
    // ---- online softmax per q row ----
    float rsc[4];
    #pragma unroll
    for (int i=0;i<4;++i){
      float tm = fmaxf(fmaxf(sv[i][0],sv[i][1]),fmaxf(sv[i][2],sv[i][3]));
      tm *= scale;
      tm = fmaxf(tm, __shfl_xor(tm,1));
      tm = fmaxf(tm, __shfl_xor(tm,2));
      tm = fmaxf(tm, __shfl_xor(tm,4));
      tm = fmaxf(tm, __shfl_xor(tm,8));
      float mnew = fmaxf(mr[i], tm);
      rsc[i] = __expf(mr[i]-mnew);
      float ts = 0.f;
      #pragma unroll
      for (int j=0;j<4;++j){ sv[i][j] = __expf(sv[i][j]*scale - mnew); ts += sv[i][j]; }
      ts += __shfl_xor(ts,1); ts += __shfl_xor(ts,2); ts += __shfl_xor(ts,4); ts += __shfl_xor(ts,8);
      lr[i] = lr[i]*rsc[i] + ts;
      mr[i] = mnew;
    }
    // write P (read back by same 16-lane group -> same-wave DS ordering, no barrier)
    #pragma unroll
    for (int i=0;i<4;++i)
      #pragma unroll
      for (int j=0;j<4;++j) Ps[q4+16*i][kg+16*j] = sv[i][j];
    #pragma unroll
    for (int i=0;i<4;++i){ acc[i][0]*=rsc[i]; acc[i][1]*=rsc[i]; }
    // ---- PV: acc[i][0..1] over 64 k ----
    #pragma unroll 4
    for (int c4=0; c4<64; c4+=4){
      float4 p0 = *(const float4*)&Ps[q4   ][c4];
      float4 p1 = *(const float4*)&Ps[q4+16][c4];
      float4 p2 = *(const float4*)&Ps[q4+32][c4];
      float4 p3 = *(const float4*)&Ps[q4+48][c4];
      float2 v0 = *(const float2*)&Vs[c4  ][d0];
      float2 v1 = *(const float2*)&Vs[c4+1][d0];
      float2 v2 = *(const float2*)&Vs[c4+2][d0];
      float2 v3 = *(const float2*)&Vs[c4+3][d0];
      acc[0][0] += p0.x*v0.x + p0.y*v1.x + p0.z*v2.x + p0.w*v3.x;
      acc[0][1] += p0.x*v0.y + p0.y*v1.y + p0.z*v2.y + p0.w*v3.y;
      acc[1][0] += p1.x*v0.x + p1.y*v1.x + p1.z*v2.x + p1.w*v3.x;
      acc[1][1] += p1.x*v0.y + p1.y*v1.y + p1.z*v2.y + p1.w*v3.y;
      acc[2][0] += p2.x*v0.x + p2.y*v1.x + p2.z*v2.x + p2.w*v3.x;
      acc[2][1] += p2.x*v0.y + p2.y*v1.y + p2.z*v2.y + p2.w*v3.y;
      acc[3][0] += p3.x*v0.x + p3.y*v1.x + p3.z*v2.x + p3.w*v3.x;
      acc[3][1] += p3.x*v0.y + p3.y*v1.y + p3.z*v2.y + p3.w*v3.y;
    }
    __syncthreads();
  }
  #pragma unroll
  for (int i=0;i<4;++i){
    float2 o2; o2.x = acc[i][0]; o2.y = acc[i][1];
    *(float2*)&Hpart[((size_t)ks*SEQ + qb*64 + q4 + 16*i)*64 + h*32 + d0] = o2;
  }
  if (kg==0){
    #pragma unroll
    for (int i=0;i<4;++i){
      float* ap = aux + ((size_t)(ks*2+h)*SEQ + qb*64 + q4 + 16*i)*2;
      ap[0]=mr[i]; ap[1]=lr[i];
    }
  }
}

__global__ __launch_bounds__(256) void flash_combine3(const float* __restrict__ Hpart,
    const float* __restrict__ aux, float* __restrict__ H){
  int t = blockIdx.x*256+threadIdx.x;
  if (t>=SEQ*64) return;
  int h = (t>>5)&1;
  int s = t>>6;
  const float* a0 = aux + ((size_t)(0+h)*SEQ + s)*2;
  const float* a1 = aux + ((size_t)(2+h)*SEQ + s)*2;
  const float* a2 = aux + ((size_t)(4+h)*SEQ + s)*2;
  float m0=a0[0], l0=a0[1], m1=a1[0], l1=a1[1], m2=a2[0], l2=a2[1];
  float ms = fmaxf(fmaxf(m0,m1),m2);
  float w0 = __expf(m0-ms), w1 = __expf(m1-ms), w2 = __expf(m2-ms);
  float inv = 1.f/(l0*w0 + l1*w1 + l2*w2);
  H[t] = (Hpart[t]*w0 + Hpart[SEQ*64+t]*w1 + Hpart[2*SEQ*64+t]*w2)*inv;
}

// ---------------- MHA output linear (+ optional residual & LN) ----------------
__global__ __launch_bounds__(256) void outlin_enc(const float* __restrict__ H, const float* __restrict__ lw,
     const float* __restrict__ lb, float* __restrict__ seqout){
  __shared__ float Ls[32*65];
  int tid=threadIdx.x;
  for (int idx=tid; idx<2048; idx+=256){ int o=idx>>6, d=idx&63; Ls[o*65+d]=lw[idx]; }
  __syncthreads();
  int t = blockIdx.x*256+tid;
  int o = t&31; int s = t>>5;
  const float* hr = H + (size_t)s*64;
  float acc = lb[o];
  #pragma unroll
  for (int d=0;d<64;++d) acc += hr[d]*Ls[o*65+d];
  seqout[t]=acc;
}

__global__ __launch_bounds__(256) void outlin_ln(const float* __restrict__ H, const float* __restrict__ lw,
    const float* __restrict__ lb, const float* __restrict__ seqin,
    const float* __restrict__ g, const float* __restrict__ b, float* __restrict__ seqout){
  __shared__ float Ls[32*65];
  int tid=threadIdx.x;
  for (int idx=tid; idx<2048; idx+=256){ int o=idx>>6, d=idx&63; Ls[o*65+d]=lw[idx]; }
  __syncthreads();
  int t = blockIdx.x*256+tid;
  int o = t&31; int s = t>>5;
  const float* hr = H + (size_t)s*64;
  float acc = lb[o] + seqin[t];
  #pragma unroll
  for (int d=0;d<64;++d) acc += hr[d]*Ls[o*65+d];
  float sum=acc;
  #pragma unroll
  for (int off=1; off<32; off<<=1) sum += __shfl_xor(sum,off);
  float mu = sum*0.03125f;
  float dv = acc-mu;
  float vs = dv*dv;
  #pragma unroll
  for (int off=1; off<32; off<<=1) vs += __shfl_xor(vs,off);
  float rstd = rsqrtf(vs*0.03125f + 1e-5f);
  seqout[t] = dv*rstd*g[o] + b[o];
}

// ---------------- per-entity output heads ----------------
__global__ __launch_bounds__(256) void head_mlp(const float* __restrict__ seq,
  const float* __restrict__ fw1,const float* __restrict__ fb1,const float* __restrict__ fa,
  const float* __restrict__ fw2,const float* __restrict__ fb2,
  const float* __restrict__ rw1,const float* __restrict__ rb1,const float* __restrict__ ra,
  const float* __restrict__ rw2,const float* __restrict__ rb2,
  float* __restrict__ out)
{
  int e = blockIdx.x*256+threadIdx.x;
  if (e>=SEQ) return;
  const float *w1,*b1,*w2,*b2; float a; int od; float* dst;
  if (e<64){ w1=fw1;b1=fb1;a=fa[0];w2=fw2;b2=fb2;od=4; dst=out + e*4; }
  else if (e<2112){ w1=rw1;b1=rb1;a=ra[0];w2=rw2;b2=rb2;od=17; dst=out + 256 + (size_t)(e-64)*17; }
  else if (e<2176){ w1=fw1;b1=fb1;a=fa[0];w2=fw2;b2=fb2;od=4; dst=out + 35072 + (e-2112)*4; }
  else { w1=rw1;b1=rb1;a=ra[0];w2=rw2;b2=rb2;od=17; dst=out + 35328 + (size_t)(e-2176)*17; }
  float x[32];
  #pragma unroll
  for (int i=0;i<32;++i) x[i]=seq[(size_t)e*32+i];
  float hbuf[32];
  #pragma unroll
  for (int j=0;j<32;++j){
    float acc=b1[j];
    #pragma unroll
    for (int i=0;i<32;++i) acc+=w1[j*32+i]*x[i];
    hbuf[j]=prelu_f(acc,a);
  }
  for (int k=0;k<od;++k){
    float acc=b2[k];
    #pragma unroll
    for (int j=0;j<32;++j) acc+=w2[k*32+j]*hbuf[j];
    dst[k]=acc;
  }
}

// ---------------- value head conv1: 66->96 @16x16, pool to 8x8 ----------------
__global__ __launch_bounds__(128) void vconv1_pool(const float* __restrict__ in, const float* __restrict__ w,
    const float* __restrict__ bias, const float* __restrict__ alpha, float* __restrict__ out){
  __shared__ float In[66*160];   // [i][r(10)][x(16)], r maps global row y0-1+r
  __shared__ float Wc[594];
  int c = blockIdx.x >> 1, half = blockIdx.x & 1;
  int y0 = half*8;
  int tid = threadIdx.x;
  const float4* in4 = (const float4*)in;
  float4* In4 = (float4*)In;
  for (int idx4=tid; idx4<2640; idx4+=128){
    int i = idx4/40, rem = idx4 - i*40;
    int r = rem>>2, x4 = rem&3;
    int y = y0 - 1 + r;
    float4 v;
    if ((unsigned)y < 16u) v = in4[i*64 + y*4 + x4];
    else { v.x=v.y=v.z=v.w=0.f; }
    In4[idx4] = v;
  }
  for (int idx=tid; idx<594; idx+=128) Wc[idx] = w[c*594 + idx];
  __syncthreads();
  int x = tid & 15, ry = tid >> 4;     // output row y0+ry
  float a = alpha[0];
  float acc = bias[c];
  for (int i=0;i<66;++i){
    const float* base = &In[i*160 + ry*16];
    const float* wp = &Wc[i*9];
    #pragma unroll
    for (int ky=0;ky<3;++ky){
      const float* row = base + ky*16;
      #pragma unroll
      for (int kx=0;kx<3;++kx){
        int xx = x+kx-1;
        float v = ((unsigned)xx<16u) ? row[xx] : 0.f;
        acc += v*wp[ky*3+kx];
      }
    }
  }
  acc = prelu_f(acc, a);
  float mx = fmaxf(acc, __shfl_xor(acc,1));
  mx = fmaxf(mx, __shfl_xor(mx,16));
  if (((x&1)==0) && ((ry&1)==0))
    out[c*64 + (half*4 + (ry>>1))*8 + (x>>1)] = mx;
}

// ---------------- value head conv2: 96->128 @8x8, pool to 4x4 ----------------
__global__ __launch_bounds__(64) void vconv2_pool(const float* __restrict__ in, const float* __restrict__ w,
    const float* __restrict__ bias, const float* __restrict__ alpha, float* __restrict__ out){
  __shared__ float In[96*64];
  __shared__ float Ws[864];
  int c = blockIdx.x;
  int tid = threadIdx.x;
  const float4* in4 = (const float4*)in;
  float4* In4 = (float4*)In;
  for (int idx4=tid; idx4<1536; idx4+=64) In4[idx4] = in4[idx4];
  for (int idx=tid; idx<864; idx+=64) Ws[idx] = w[c*864 + idx];
  __syncthreads();
  int x = tid&7, y = tid>>3;
  float acc = bias[c];
  for (int i=0;i<96;++i){
    const float* base = &In[i*64];
    const float* wp = &Ws[i*9];
    #pragma unroll
    for (int ky=0;ky<3;++ky){
      int yy = y+ky-1;
      #pragma unroll
      for (int kx=0;kx<3;++kx){
        int xx = x+kx-1;
        bool ok = ((unsigned)yy<8u) && ((unsigned)xx<8u);
        float v = ok ? base[yy*8+xx] : 0.f;
        acc += v*wp[ky*3+kx];
      }
    }
  }
  acc = prelu_f(acc, alpha[0]);
  float mx = fmaxf(acc, __shfl_xor(acc,1));
  mx = fmaxf(mx, __shfl_xor(mx,8));
  if (((x&1)==0) && ((y&1)==0))
    out[c*16 + (y>>1)*4 + (x>>1)] = mx;
}

__global__ __launch_bounds__(256) void vfinal(const float* __restrict__ vp2, const float* __restrict__ lw,
                       const float* __restrict__ lb, float* __restrict__ outv){
  __shared__ float red[256];
  int tid=threadIdx.x;
  float s=0.f;
  for (int i=tid;i<2048;i+=256) s += vp2[i]*lw[i];
  red[tid]=s; __syncthreads();
  for (int k=128;k>0;k>>=1){ if (tid<k) red[tid]+=red[tid+k]; __syncthreads(); }
  if (tid==0) outv[0] = tanhf(red[0]+lb[0]);
}

// ---------------- host ----------------
extern "C" void kernel_launch(void* const* d_in, const int* in_sizes, int n_in,
                              void* d_out, int out_size, void* d_ws, size_t ws_size,
                              hipStream_t stream){
  (void)in_sizes; (void)n_in; (void)out_size; (void)ws_size;
  const float* board = (const float*)d_in[0];
  const float* p0f = (const float*)d_in[1];
  const float* p0u = (const float*)d_in[2];
  const float* p1f = (const float*)d_in[3];
  const float* p1u = (const float*)d_in[4];
  const float* sp_w1=(const float*)d_in[5];  const float* sp_b1=(const float*)d_in[6];  const float* sp_a1=(const float*)d_in[7];
  const float* sp_w2=(const float*)d_in[8];  const float* sp_b2=(const float*)d_in[9];  const float* sp_a2=(const float*)d_in[10];
  const float* sp_w3=(const float*)d_in[11]; const float* sp_b3=(const float*)d_in[12];
  const float* enc_fac_w=(const float*)d_in[13]; const float* enc_fac_b=(const float*)d_in[14];
  const float* enc_unit_w=(const float*)d_in[15]; const float* enc_unit_b=(const float*)d_in[16];
  const float* enc_lin_w=(const float*)d_in[17]; const float* enc_lin_b=(const float*)d_in[18];
  const float* ext_fac_w=(const float*)d_in[19]; const float* ext_fac_b=(const float*)d_in[20];
  const float* ext_unit_w=(const float*)d_in[21]; const float* ext_unit_b=(const float*)d_in[22];
  const float* ext_lin_w=(const float*)d_in[23]; const float* ext_lin_b=(const float*)d_in[24];
  const float* ext_ln_g=(const float*)d_in[25]; const float* ext_ln_b=(const float*)d_in[26];
  const float* v_w1=(const float*)d_in[27]; const float* v_b1=(const float*)d_in[28]; const float* v_a1=(const float*)d_in[29];
  const float* v_w2=(const float*)d_in[30]; const float* v_b2=(const float*)d_in[31]; const float* v_a2=(const float*)d_in[32];
  const float* v_lw=(const float*)d_in[33]; const float* v_lb=(const float*)d_in[34];
  const float* fo_w1=(const float*)d_in[35]; const float* fo_b1=(const float*)d_in[36]; const float* fo_a=(const float*)d_in[37];
  const float* fo_w2=(const float*)d_in[38]; const float* fo_b2=(const float*)d_in[39];
  const float* ro_w1=(const float*)d_in[40]; const float* ro_b1=(const float*)d_in[41]; const float* ro_a=(const float*)d_in[42];
  const float* ro_w2=(const float*)d_in[43]; const float* ro_b2=(const float*)d_in[44];
  const int* p0fp=(const int*)d_in[45]; const int* p0up=(const int*)d_in[46];
  const int* p1fp=(const int*)d_in[47]; const int* p1up=(const int*)d_in[48];
  float* out = (float*)d_out;

  float* W = (float*)d_ws;
  float* sm1 = W;                    // 48*48*48
  float* sm2 = sm1 + 110592;         // 96*48*48
  float* sm  = sm2 + 221184;         // 24*16*16
  float* F0  = sm + 6144;            // 64*31
  float* U0  = F0 + 1984;            // 2048*38
  float* F1  = U0 + 77824;           // 64*31
  float* U1  = F1 + 1984;            // 2048*38
  float* Qb  = U1 + 77824;           // 2*SEQ*32
  float* Kb  = Qb + 2*SEQ*32;
  float* Vb  = Kb + 2*SEQ*32;
  float* Hp  = Vb + 2*SEQ*32;        // 3*SEQ*64 (ksplit partials)
  float* aux = Hp + 3*SEQ*64;        // 3*2*SEQ*2
  float* Hh  = aux + 3*2*SEQ*2;      // SEQ*64
  float* seqA= Hh + SEQ*64;          // SEQ*32
  float* seqB= seqA + SEQ*32;        // SEQ*32
  float* vmap= seqB + SEQ*32;        // 66*256
  float* vp1 = vmap + 66*256;        // 96*64
  float* vp2 = vp1 + 96*64;          // 128*16

  // spatial path
  conv3x3_v2<14,48,48,1,4><<<108,256,0,stream>>>(board, sp_w1, sp_b1, sp_a1, sm1);
  conv3x3_v2<48,96,48,1,4><<<216,256,0,stream>>>(sm1, sp_w2, sp_b2, sp_a2, sm2);
  conv_s3_v2<<<12,256,0,stream>>>(sm2, sp_w3, sp_b3, sm);
  gather_concat<<<17,256,0,stream>>>(sm, p0f,p0u,p1f,p1u, p0fp,p0up,p1fp,p1up, F0,U0,F1,U1);
  vmap_init<<<66,256,0,stream>>>(sm, vmap);
  vmap_scatter<<<17,256,0,stream>>>(p0f,p0u,p1f,p1u, p0fp,p0up,p1fp,p1up, vmap);
  // value head
  vconv1_pool<<<192,128,0,stream>>>(vmap, v_w1, v_b1, v_a1, vp1);
  vconv2_pool<<<128,64,0,stream>>>(vp1, v_w2, v_b2, v_a2, vp2);
  vfinal<<<1,256,0,stream>>>(vp2, v_lw, v_lb, out + 70144);

  // encoder layer
  qkv_proj<<<396,256,0,stream>>>(F0,U0,F1,U1, 31,38, enc_fac_w,enc_fac_b,enc_unit_w,enc_unit_b, Qb,Kb,Vb);
  flash_attn2<<<dim3(66,2,3),256,0,stream>>>(Qb,Kb,Vb,Hp,aux);
  flash_combine3<<<1056,256,0,stream>>>(Hp,aux,Hh);
  outlin_enc<<<528,256,0,stream>>>(Hh, enc_lin_w, enc_lin_b, seqA);
  // extractor layer 0
  qkv_proj<<<396,256,0,stream>>>(seqA, seqA+64*32, seqA+2112*32, seqA+2176*32, 32,32,
      ext_fac_w, ext_fac_b, ext_unit_w, ext_unit_b, Qb,Kb,Vb);
  flash_attn2<<<dim3(66,2,3),256,0,stream>>>(Qb,Kb,Vb,Hp,aux);
  flash_combine3<<<1056,256,0,stream>>>(Hp,aux,Hh);
  outlin_ln<<<528,256,0,stream>>>(Hh, ext_lin_w, ext_lin_b, seqA, ext_ln_g, ext_ln_b, seqB);
  // extractor layer 1
  qkv_proj<<<396,256,0,stream>>>(seqB, seqB+64*32, seqB+2112*32, seqB+2176*32, 32,32,
      ext_fac_w+12288, ext_fac_b+384, ext_unit_w+12288, ext_unit_b+384, Qb,Kb,Vb);
  flash_attn2<<<dim3(66,2,3),256,0,stream>>>(Qb,Kb,Vb,Hp,aux);
  flash_combine3<<<1056,256,0,stream>>>(Hp,aux,Hh);
  outlin_ln<<<528,256,0,stream>>>(Hh, ext_lin_w+2048, ext_lin_b+32, seqB, ext_ln_g+32, ext_ln_b+32, seqA);

  head_mlp<<<17,256,0,stream>>>(seqA, fo_w1,fo_b1,fo_a,fo_w2,fo_b2, ro_w1,ro_b1,ro_a,ro_w2,ro_b2, out);
}

// Round 3
// 420.811 us; speedup vs baseline: 3.2993x; 1.7379x over previous
//
#include <hip/hip_runtime.h>

#define SEQ 4224
typedef unsigned int uint;
typedef unsigned short ushort;
typedef __attribute__((ext_vector_type(8))) short bf16x8;
typedef __attribute__((ext_vector_type(4))) float f32x4;

__device__ __forceinline__ float prelu_f(float x, float a){ return x > 0.f ? x : a*x; }

__device__ __forceinline__ ushort bfr(float x){
  uint u = __float_as_uint(x);
  u = (u + 0x7fffu + ((u>>16)&1u)) >> 16;
  return (ushort)u;
}
__device__ __forceinline__ uint bfp2(float a, float b){
  uint ua = __float_as_uint(a); ua = (ua + 0x7fffu + ((ua>>16)&1u)) >> 16;
  uint ub = __float_as_uint(b); ub = (ub + 0x7fffu + ((ub>>16)&1u)) & 0xffff0000u;
  return (ua & 0xffffu) | ub;
}

// ---------------- spatial convs (weights in LDS, CPT channels/thread) ----------------
template<int CIN, int COUT, int HW, int ACT, int CPT>
__global__ __launch_bounds__(256) void conv3x3_v2(const float* __restrict__ in, const float* __restrict__ w,
                          const float* __restrict__ bias, const float* __restrict__ alpha,
                          float* __restrict__ out) {
  __shared__ float Ws[CPT*CIN*9];
  __shared__ float Bs[CPT];
  const int PXB = HW*HW/256;
  int cg = blockIdx.x / PXB, pxb = blockIdx.x % PXB;
  int tid = threadIdx.x;
  for (int idx=tid; idx<CPT*CIN*9; idx+=256) Ws[idx] = w[cg*CPT*CIN*9 + idx];
  if (tid<CPT) Bs[tid] = bias[cg*CPT+tid];
  __syncthreads();
  int p = pxb*256 + tid;
  int x = p % HW, y = p / HW;
  float a = ACT ? alpha[0] : 0.f;
  float acc[CPT];
  #pragma unroll
  for (int c=0;c<CPT;++c) acc[c]=Bs[c];
  #pragma unroll 2
  for (int i=0;i<CIN;++i){
    const float* ip = in + i*HW*HW;
    float win[9];
    #pragma unroll
    for (int ky=0;ky<3;++ky){
      int yy = y+ky-1;
      #pragma unroll
      for (int kx=0;kx<3;++kx){
        int xx = x+kx-1;
        bool ok = ((unsigned)yy < (unsigned)HW) && ((unsigned)xx < (unsigned)HW);
        win[ky*3+kx] = ok ? ip[yy*HW+xx] : 0.f;
      }
    }
    #pragma unroll
    for (int c=0;c<CPT;++c){
      const float* wp = &Ws[(c*CIN+i)*9];
      #pragma unroll
      for (int k=0;k<9;++k) acc[c] += win[k]*wp[k];
    }
  }
  #pragma unroll
  for (int c=0;c<CPT;++c){
    float v = acc[c];
    if (ACT) v = prelu_f(v, a);
    out[(cg*CPT+c)*HW*HW + p] = v;
  }
}

// stride-3 valid conv 96->24 over 48x48 -> 16x16; 2 channels per block
__global__ __launch_bounds__(256) void conv_s3_v2(const float* __restrict__ in, const float* __restrict__ w,
                        const float* __restrict__ bias, float* __restrict__ out) {
  __shared__ float Ws[2*96*9];
  int cg = blockIdx.x;   // 12 blocks
  int tid = threadIdx.x;
  for (int idx=tid; idx<1728; idx+=256) Ws[idx] = w[cg*1728 + idx];
  __syncthreads();
  int x = tid&15, y = tid>>4;
  float a0 = bias[2*cg], a1 = bias[2*cg+1];
  const float* ip0 = in + y*144 + x*3;
  #pragma unroll 4
  for (int i=0;i<96;++i){
    const float* ip = ip0 + i*2304;
    float win[9];
    #pragma unroll
    for (int ky=0;ky<3;++ky)
      #pragma unroll
      for (int kx=0;kx<3;++kx) win[ky*3+kx] = ip[ky*48+kx];
    const float* w0 = &Ws[i*9];
    const float* w1 = &Ws[864 + i*9];
    #pragma unroll
    for (int k=0;k<9;++k){ a0 += win[k]*w0[k]; a1 += win[k]*w1[k]; }
  }
  out[(2*cg)*256 + y*16 + x] = a0;
  out[(2*cg+1)*256 + y*16 + x] = a1;
}

// ---------------- gather + concat entity features ----------------
__global__ __launch_bounds__(256) void gather_concat(const float* __restrict__ sm,
  const float* __restrict__ p0f, const float* __restrict__ p0u,
  const float* __restrict__ p1f, const float* __restrict__ p1u,
  const int* __restrict__ p0fp, const int* __restrict__ p0up,
  const int* __restrict__ p1fp, const int* __restrict__ p1up,
  float* __restrict__ F0, float* __restrict__ U0, float* __restrict__ F1, float* __restrict__ U1)
{
  int e = blockIdx.x*256+threadIdx.x;
  if (e>=SEQ) return;
  const float* feat; const int* pos; float* dst; int nf, n;
  if (e<64){ n=e; feat=p0f+n*7; pos=p0fp; dst=F0+n*31; nf=7; }
  else if (e<2112){ n=e-64; feat=p0u+n*14; pos=p0up; dst=U0+(size_t)n*38; nf=14; }
  else if (e<2176){ n=e-2112; feat=p1f+n*7; pos=p1fp; dst=F1+n*31; nf=7; }
  else { n=e-2176; feat=p1u+n*14; pos=p1up; dst=U1+(size_t)n*38; nf=14; }
  for (int c=0;c<nf;++c) dst[c]=feat[c];
  int px = pos[2*n], py = pos[2*n+1];
  const float* s = sm + px*16 + py;
  #pragma unroll
  for (int c=0;c<24;++c) dst[nf+c] = s[c*256];
}

// ---------------- value-map build ----------------
__global__ __launch_bounds__(256) void vmap_init(const float* __restrict__ sm, float* __restrict__ vmap){
  int t = blockIdx.x*256+threadIdx.x;
  if (t>=66*256) return;
  int c = t>>8;
  vmap[t] = (c<42)? 0.f : sm[t - 42*256];
}

__global__ __launch_bounds__(256) void vmap_scatter(
  const float* __restrict__ p0f, const float* __restrict__ p0u,
  const float* __restrict__ p1f, const float* __restrict__ p1u,
  const int* __restrict__ p0fp, const int* __restrict__ p0up,
  const int* __restrict__ p1fp, const int* __restrict__ p1up,
  float* __restrict__ vmap)
{
  int e = blockIdx.x*256+threadIdx.x;
  if (e>=SEQ) return;
  const float* feat; const int* pos; int n, ch0, C;
  if (e<2048){ n=e; feat=p1u+n*14; pos=p1up; ch0=0; C=14; }
  else if (e<2112){ n=e-2048; feat=p1f+n*7; pos=p1fp; ch0=14; C=7; }
  else if (e<4160){ n=e-2112; feat=p0u+n*14; pos=p0up; ch0=21; C=14; }
  else { n=e-4160; feat=p0f+n*7; pos=p0fp; ch0=35; C=7; }
  int off = pos[2*n]*16 + pos[2*n+1];
  for (int c=0;c<C;++c) atomicAdd(&vmap[(ch0+c)*256 + off], feat[c]);
}

// ---------------- QKV projection -> bf16 Q(scaled), K, V^T ----------------
__global__ __launch_bounds__(256) void qkv_proj(const float* __restrict__ x0, const float* __restrict__ x1,
    const float* __restrict__ x2, const float* __restrict__ x3, int ind_f, int ind_u,
    const float* __restrict__ fw, const float* __restrict__ fb,
    const float* __restrict__ uw, const float* __restrict__ ub,
    ushort* __restrict__ Q16, ushort* __restrict__ K16, ushort* __restrict__ VT16){
  __shared__ float Xs[64*38];
  __shared__ float Ws[32*39];
  __shared__ float Bs[32];
  int blk = blockIdx.x;
  int chunk = blk % 66;
  int hm = blk / 66;       // 0..5 = m*2+h
  int m = hm >> 1, h = hm & 1;
  const float* xb; int ind, isfac, pl;
  if (chunk==0){ xb=x0; ind=ind_f; isfac=1; pl=0; }
  else if (chunk<=32){ xb=x1 + (size_t)(chunk-1)*64*ind_u; ind=ind_u; isfac=0; pl=0; }
  else if (chunk==33){ xb=x2; ind=ind_f; isfac=1; pl=1; }
  else { xb=x3 + (size_t)(chunk-34)*64*ind_u; ind=ind_u; isfac=0; pl=1; }
  int b0 = h*6 + pl*3 + m;
  const float* w = (isfac? fw:uw) + (size_t)b0*32*ind;
  const float* bias = (isfac? fb:ub) + b0*32;
  int tid = threadIdx.x;
  for (int idx=tid; idx<64*ind; idx+=256) Xs[idx]=xb[idx];
  for (int idx=tid; idx<32*ind; idx+=256){ int oo=idx/ind, dd=idx-oo*ind; Ws[oo*39+dd]=w[idx]; }
  if (tid<32) Bs[tid]=bias[tid];
  __syncthreads();
  int o = tid&31, r0 = tid>>5;
  const float* xr[8];
  #pragma unroll
  for (int j=0;j<8;++j) xr[j] = &Xs[(r0+8*j)*ind];
  float acc[8];
  #pragma unroll
  for (int j=0;j<8;++j) acc[j]=Bs[o];
  for (int d=0; d<ind; ++d){
    float wv = Ws[o*39+d];
    #pragma unroll
    for (int j=0;j<8;++j) acc[j] += xr[j][d]*wv;
  }
  if (m==0){
    // Q: fold 1/sqrt(32)
    ushort* base = Q16 + ((size_t)h*SEQ + chunk*64)*32 + o;
    #pragma unroll
    for (int j=0;j<8;++j) base[(r0+8*j)*32] = bfr(acc[j]*0.17677669529663687f);
  } else if (m==1){
    ushort* base = K16 + ((size_t)h*SEQ + chunk*64)*32 + o;
    #pragma unroll
    for (int j=0;j<8;++j) base[(r0+8*j)*32] = bfr(acc[j]);
  } else {
    // V transposed: VT[h][d=o][seq]
    ushort* base = VT16 + ((size_t)h*32 + o)*SEQ + chunk*64;
    #pragma unroll
    for (int j=0;j<8;++j) base[r0+8*j] = bfr(acc[j]);
  }
}

// ---------------- MFMA flash attention (bf16 in, fp32 stats/acc) ----------------
// grid (66 qb, 2 h, 3 ks); block 256 = 4 waves; wave w owns q-rows w*16..w*16+15.
// S^T = K*Q^T via mfma_16x16x32: lane holds S[q=l&15][k=16m+(l>>4)*4+r].
#define KSPLIT 3
#define KITERS 22
__global__ __launch_bounds__(256) void flash_mfma(const ushort* __restrict__ Q16,
    const ushort* __restrict__ K16, const ushort* __restrict__ VT16,
    float* __restrict__ Hpart, float* __restrict__ aux){
  __shared__ ushort Ks[64][40];   // row stride 80B
  __shared__ ushort VTs[32][80];  // row stride 160B
  __shared__ ushort Pl[4][16][72];// per-wave P, row stride 144B
  int qb = blockIdx.x, h = blockIdx.y, ks = blockIdx.z;
  int tid = threadIdx.x;
  int wv = tid>>6, l = tid&63, lq = l&15, g = l>>4;
  const ushort* Qh = Q16 + (size_t)h*SEQ*32;
  const ushort* Kh = K16 + (size_t)h*SEQ*32;
  const ushort* VTh = VT16 + (size_t)h*32*SEQ;

  // Q B-frag (held whole kernel): lane gives Q[q=lq][d=g*8..g*8+7]
  bf16x8 qf = *(const bf16x8*)(Qh + (size_t)(qb*64 + wv*16 + lq)*32 + g*8);

  // staging assignments (coalesced)
  int krow = tid>>2, kc8 = (tid&3)*8;       // K: 4 threads/row
  int vd = tid>>3, vk8 = (tid&7)*8;         // VT: 8 threads/row

  f32x4 o0 = {0.f,0.f,0.f,0.f}, o1 = {0.f,0.f,0.f,0.f};
  float mr = -1e30f, lrow = 0.f;

  int kt0 = ks*KITERS;
  bf16x8 kpre = *(const bf16x8*)(Kh + (size_t)(kt0*64 + krow)*32 + kc8);
  bf16x8 vpre = *(const bf16x8*)(VTh + (size_t)vd*SEQ + kt0*64 + vk8);

  for (int it=0; it<KITERS; ++it){
    *(bf16x8*)&Ks[krow][kc8] = kpre;
    *(bf16x8*)&VTs[vd][vk8] = vpre;
    __syncthreads();
    if (it < KITERS-1){
      kpre = *(const bf16x8*)(Kh + (size_t)((kt0+it+1)*64 + krow)*32 + kc8);
      vpre = *(const bf16x8*)(VTh + (size_t)vd*SEQ + (kt0+it+1)*64 + vk8);
    }
    // ---- QK^T (swapped): 4 m-tiles over 64 k ----
    f32x4 z = {0.f,0.f,0.f,0.f};
    f32x4 sT[4];
    #pragma unroll
    for (int m=0;m<4;++m){
      bf16x8 kf = *(const bf16x8*)&Ks[16*m + lq][g*8];
      sT[m] = __builtin_amdgcn_mfma_f32_16x16x32_bf16(kf, qf, z, 0, 0, 0);
    }
    // ---- online softmax: lane has 16 k-values of row q=lq ----
    float tm = -1e30f;
    #pragma unroll
    for (int m=0;m<4;++m){
      tm = fmaxf(tm, fmaxf(fmaxf(sT[m][0],sT[m][1]), fmaxf(sT[m][2],sT[m][3])));
    }
    tm = fmaxf(tm, __shfl_xor(tm,16));
    tm = fmaxf(tm, __shfl_xor(tm,32));
    float mnew = fmaxf(mr, tm);
    float rsc = __expf(mr - mnew);
    float ts = 0.f;
    #pragma unroll
    for (int m=0;m<4;++m){
      #pragma unroll
      for (int r=0;r<4;++r){ float p = __expf(sT[m][r]-mnew); sT[m][r]=p; ts+=p; }
    }
    ts += __shfl_xor(ts,16); ts += __shfl_xor(ts,32);
    lrow = lrow*rsc + ts; mr = mnew;
    // pack P -> LDS (bf16), row q=lq, k=16m+g*4+{0..3}
    #pragma unroll
    for (int m=0;m<4;++m){
      uint2 pw; pw.x = bfp2(sT[m][0],sT[m][1]); pw.y = bfp2(sT[m][2],sT[m][3]);
      *(uint2*)&Pl[wv][lq][16*m + g*4] = pw;
    }
    // rescale O: O rows are q'=(g*4+r) -> fetch rsc of q' via shfl
    float rr0 = __shfl(rsc, (g<<2)+0);
    float rr1 = __shfl(rsc, (g<<2)+1);
    float rr2 = __shfl(rsc, (g<<2)+2);
    float rr3 = __shfl(rsc, (g<<2)+3);
    o0[0]*=rr0; o0[1]*=rr1; o0[2]*=rr2; o0[3]*=rr3;
    o1[0]*=rr0; o1[1]*=rr1; o1[2]*=rr2; o1[3]*=rr3;
    // ---- PV: O(16q x 32d) += P(16x64)*V(64x32) ----
    #pragma unroll
    for (int s=0;s<2;++s){
      bf16x8 pf = *(const bf16x8*)&Pl[wv][lq][s*32 + g*8];
      bf16x8 vf0 = *(const bf16x8*)&VTs[lq][s*32 + g*8];
      bf16x8 vf1 = *(const bf16x8*)&VTs[lq+16][s*32 + g*8];
      o0 = __builtin_amdgcn_mfma_f32_16x16x32_bf16(pf, vf0, o0, 0, 0, 0);
      o1 = __builtin_amdgcn_mfma_f32_16x16x32_bf16(pf, vf1, o1, 0, 0, 0);
    }
    __syncthreads();
  }
  int qg0 = qb*64 + wv*16;
  #pragma unroll
  for (int r=0;r<4;++r){
    size_t row = (size_t)ks*SEQ + qg0 + g*4 + r;
    Hpart[row*64 + h*32 + lq]      = o0[r];
    Hpart[row*64 + h*32 + lq + 16] = o1[r];
  }
  if (g==0){
    float* ap = aux + ((size_t)(ks*2+h)*SEQ + qg0 + lq)*2;
    ap[0]=mr; ap[1]=lrow;
  }
}

// ---------------- MHA output linear with fused k-split combine ----------------
__device__ __forceinline__ void combine_w(const float* __restrict__ aux, int s, float cw[2][3]){
  #pragma unroll
  for (int h=0;h<2;++h){
    float m0 = aux[((size_t)(0+h)*SEQ + s)*2], l0 = aux[((size_t)(0+h)*SEQ + s)*2+1];
    float m1 = aux[((size_t)(2+h)*SEQ + s)*2], l1 = aux[((size_t)(2+h)*SEQ + s)*2+1];
    float m2 = aux[((size_t)(4+h)*SEQ + s)*2], l2 = aux[((size_t)(4+h)*SEQ + s)*2+1];
    float ms = fmaxf(fmaxf(m0,m1),m2);
    float w0 = __expf(m0-ms), w1 = __expf(m1-ms), w2 = __expf(m2-ms);
    float inv = 1.f/(l0*w0 + l1*w1 + l2*w2);
    cw[h][0]=w0*inv; cw[h][1]=w1*inv; cw[h][2]=w2*inv;
  }
}

__global__ __launch_bounds__(256) void outlin_enc2(const float* __restrict__ Hp,
     const float* __restrict__ aux, const float* __restrict__ lw,
     const float* __restrict__ lb, float* __restrict__ seqout){
  __shared__ float Ls[32*65];
  int tid=threadIdx.x;
  for (int idx=tid; idx<2048; idx+=256){ int o=idx>>6, d=idx&63; Ls[o*65+d]=lw[idx]; }
  __syncthreads();
  int t = blockIdx.x*256+tid;
  int o = t&31; int s = t>>5;
  float cw[2][3];
  combine_w(aux, s, cw);
  const float* h0 = Hp + (size_t)s*64;
  const float* h1 = Hp + (size_t)SEQ*64 + s*64;
  const float* h2 = Hp + (size_t)2*SEQ*64 + s*64;
  float acc = lb[o];
  #pragma unroll
  for (int d=0;d<64;++d){
    int hh = d>>5;
    float hv = h0[d]*cw[hh][0] + h1[d]*cw[hh][1] + h2[d]*cw[hh][2];
    acc += hv*Ls[o*65+d];
  }
  seqout[t]=acc;
}

__global__ __launch_bounds__(256) void outlin_ln2(const float* __restrict__ Hp,
    const float* __restrict__ aux, const float* __restrict__ lw,
    const float* __restrict__ lb, const float* __restrict__ seqin,
    const float* __restrict__ g, const float* __restrict__ b, float* __restrict__ seqout){
  __shared__ float Ls[32*65];
  int tid=threadIdx.x;
  for (int idx=tid; idx<2048; idx+=256){ int o=idx>>6, d=idx&63; Ls[o*65+d]=lw[idx]; }
  __syncthreads();
  int t = blockIdx.x*256+tid;
  int o = t&31; int s = t>>5;
  float cw[2][3];
  combine_w(aux, s, cw);
  const float* h0 = Hp + (size_t)s*64;
  const float* h1 = Hp + (size_t)SEQ*64 + s*64;
  const float* h2 = Hp + (size_t)2*SEQ*64 + s*64;
  float acc = lb[o] + seqin[t];
  #pragma unroll
  for (int d=0;d<64;++d){
    int hh = d>>5;
    float hv = h0[d]*cw[hh][0] + h1[d]*cw[hh][1] + h2[d]*cw[hh][2];
    acc += hv*Ls[o*65+d];
  }
  float sum=acc;
  #pragma unroll
  for (int off=1; off<32; off<<=1) sum += __shfl_xor(sum,off);
  float mu = sum*0.03125f;
  float dv = acc-mu;
  float vs = dv*dv;
  #pragma unroll
  for (int off=1; off<32; off<<=1) vs += __shfl_xor(vs,off);
  float rstd = rsqrtf(vs*0.03125f + 1e-5f);
  seqout[t] = dv*rstd*g[o] + b[o];
}

// ---------------- per-entity output heads ----------------
__global__ __launch_bounds__(256) void head_mlp(const float* __restrict__ seq,
  const float* __restrict__ fw1,const float* __restrict__ fb1,const float* __restrict__ fa,
  const float* __restrict__ fw2,const float* __restrict__ fb2,
  const float* __restrict__ rw1,const float* __restrict__ rb1,const float* __restrict__ ra,
  const float* __restrict__ rw2,const float* __restrict__ rb2,
  float* __restrict__ out)
{
  int e = blockIdx.x*256+threadIdx.x;
  if (e>=SEQ) return;
  const float *w1,*b1,*w2,*b2; float a; int od; float* dst;
  if (e<64){ w1=fw1;b1=fb1;a=fa[0];w2=fw2;b2=fb2;od=4; dst=out + e*4; }
  else if (e<2112){ w1=rw1;b1=rb1;a=ra[0];w2=rw2;b2=rb2;od=17; dst=out + 256 + (size_t)(e-64)*17; }
  else if (e<2176){ w1=fw1;b1=fb1;a=fa[0];w2=fw2;b2=fb2;od=4; dst=out + 35072 + (e-2112)*4; }
  else { w1=rw1;b1=rb1;a=ra[0];w2=rw2;b2=rb2;od=17; dst=out + 35328 + (size_t)(e-2176)*17; }
  float x[32];
  #pragma unroll
  for (int i=0;i<32;++i) x[i]=seq[(size_t)e*32+i];
  float hbuf[32];
  #pragma unroll
  for (int j=0;j<32;++j){
    float acc=b1[j];
    #pragma unroll
    for (int i=0;i<32;++i) acc+=w1[j*32+i]*x[i];
    hbuf[j]=prelu_f(acc,a);
  }
  for (int k=0;k<od;++k){
    float acc=b2[k];
    #pragma unroll
    for (int j=0;j<32;++j) acc+=w2[k*32+j]*hbuf[j];
    dst[k]=acc;
  }
}

// ---------------- value head conv1: 66->96 @16x16, pool to 8x8 ----------------
__global__ __launch_bounds__(128) void vconv1_pool(const float* __restrict__ in, const float* __restrict__ w,
    const float* __restrict__ bias, const float* __restrict__ alpha, float* __restrict__ out){
  __shared__ float In[66*160];   // [i][r(10)][x(16)]
  __shared__ float Wc[594];
  int c = blockIdx.x >> 1, half = blockIdx.x & 1;
  int y0 = half*8;
  int tid = threadIdx.x;
  const float4* in4 = (const float4*)in;
  float4* In4 = (float4*)In;
  for (int idx4=tid; idx4<2640; idx4+=128){
    int i = idx4/40, rem = idx4 - i*40;
    int r = rem>>2, x4 = rem&3;
    int y = y0 - 1 + r;
    float4 v;
    if ((unsigned)y < 16u) v = in4[i*64 + y*4 + x4];
    else { v.x=v.y=v.z=v.w=0.f; }
    In4[idx4] = v;
  }
  for (int idx=tid; idx<594; idx+=128) Wc[idx] = w[c*594 + idx];
  __syncthreads();
  int x = tid & 15, ry = tid >> 4;
  float a = alpha[0];
  float acc = bias[c];
  for (int i=0;i<66;++i){
    const float* base = &In[i*160 + ry*16];
    const float* wp = &Wc[i*9];
    #pragma unroll
    for (int ky=0;ky<3;++ky){
      const float* row = base + ky*16;
      #pragma unroll
      for (int kx=0;kx<3;++kx){
        int xx = x+kx-1;
        float v = ((unsigned)xx<16u) ? row[xx] : 0.f;
        acc += v*wp[ky*3+kx];
      }
    }
  }
  acc = prelu_f(acc, a);
  float mx = fmaxf(acc, __shfl_xor(acc,1));
  mx = fmaxf(mx, __shfl_xor(mx,16));
  if (((x&1)==0) && ((ry&1)==0))
    out[c*64 + (half*4 + (ry>>1))*8 + (x>>1)] = mx;
}

// ---------------- value head conv2: 96->128 @8x8, pool to 4x4 ----------------
__global__ __launch_bounds__(64) void vconv2_pool(const float* __restrict__ in, const float* __restrict__ w,
    const float* __restrict__ bias, const float* __restrict__ alpha, float* __restrict__ out){
  __shared__ float In[96*64];
  __shared__ float Ws[864];
  int c = blockIdx.x;
  int tid = threadIdx.x;
  const float4* in4 = (const float4*)in;
  float4* In4 = (float4*)In;
  for (int idx4=tid; idx4<1536; idx4+=64) In4[idx4] = in4[idx4];
  for (int idx=tid; idx<864; idx+=64) Ws[idx] = w[c*864 + idx];
  __syncthreads();
  int x = tid&7, y = tid>>3;
  float acc = bias[c];
  for (int i=0;i<96;++i){
    const float* base = &In[i*64];
    const float* wp = &Ws[i*9];
    #pragma unroll
    for (int ky=0;ky<3;++ky){
      int yy = y+ky-1;
      #pragma unroll
      for (int kx=0;kx<3;++kx){
        int xx = x+kx-1;
        bool ok = ((unsigned)yy<8u) && ((unsigned)xx<8u);
        float v = ok ? base[yy*8+xx] : 0.f;
        acc += v*wp[ky*3+kx];
      }
    }
  }
  acc = prelu_f(acc, alpha[0]);
  float mx = fmaxf(acc, __shfl_xor(acc,1));
  mx = fmaxf(mx, __shfl_xor(mx,8));
  if (((x&1)==0) && ((y&1)==0))
    out[c*16 + (y>>1)*4 + (x>>1)] = mx;
}

__global__ __launch_bounds__(256) void vfinal(const float* __restrict__ vp2, const float* __restrict__ lw,
                       const float* __restrict__ lb, float* __restrict__ outv){
  __shared__ float red[256];
  int tid=threadIdx.x;
  float s=0.f;
  for (int i=tid;i<2048;i+=256) s += vp2[i]*lw[i];
  red[tid]=s; __syncthreads();
  for (int k=128;k>0;k>>=1){ if (tid<k) red[tid]+=red[tid+k]; __syncthreads(); }
  if (tid==0) outv[0] = tanhf(red[0]+lb[0]);
}

// ---------------- host ----------------
extern "C" void kernel_launch(void* const* d_in, const int* in_sizes, int n_in,
                              void* d_out, int out_size, void* d_ws, size_t ws_size,
                              hipStream_t stream){
  (void)in_sizes; (void)n_in; (void)out_size; (void)ws_size;
  const float* board = (const float*)d_in[0];
  const float* p0f = (const float*)d_in[1];
  const float* p0u = (const float*)d_in[2];
  const float* p1f = (const float*)d_in[3];
  const float* p1u = (const float*)d_in[4];
  const float* sp_w1=(const float*)d_in[5];  const float* sp_b1=(const float*)d_in[6];  const float* sp_a1=(const float*)d_in[7];
  const float* sp_w2=(const float*)d_in[8];  const float* sp_b2=(const float*)d_in[9];  const float* sp_a2=(const float*)d_in[10];
  const float* sp_w3=(const float*)d_in[11]; const float* sp_b3=(const float*)d_in[12];
  const float* enc_fac_w=(const float*)d_in[13]; const float* enc_fac_b=(const float*)d_in[14];
  const float* enc_unit_w=(const float*)d_in[15]; const float* enc_unit_b=(const float*)d_in[16];
  const float* enc_lin_w=(const float*)d_in[17]; const float* enc_lin_b=(const float*)d_in[18];
  const float* ext_fac_w=(const float*)d_in[19]; const float* ext_fac_b=(const float*)d_in[20];
  const float* ext_unit_w=(const float*)d_in[21]; const float* ext_unit_b=(const float*)d_in[22];
  const float* ext_lin_w=(const float*)d_in[23]; const float* ext_lin_b=(const float*)d_in[24];
  const float* ext_ln_g=(const float*)d_in[25]; const float* ext_ln_b=(const float*)d_in[26];
  const float* v_w1=(const float*)d_in[27]; const float* v_b1=(const float*)d_in[28]; const float* v_a1=(const float*)d_in[29];
  const float* v_w2=(const float*)d_in[30]; const float* v_b2=(const float*)d_in[31]; const float* v_a2=(const float*)d_in[32];
  const float* v_lw=(const float*)d_in[33]; const float* v_lb=(const float*)d_in[34];
  const float* fo_w1=(const float*)d_in[35]; const float* fo_b1=(const float*)d_in[36]; const float* fo_a=(const float*)d_in[37];
  const float* fo_w2=(const float*)d_in[38]; const float* fo_b2=(const float*)d_in[39];
  const float* ro_w1=(const float*)d_in[40]; const float* ro_b1=(const float*)d_in[41]; const float* ro_a=(const float*)d_in[42];
  const float* ro_w2=(const float*)d_in[43]; const float* ro_b2=(const float*)d_in[44];
  const int* p0fp=(const int*)d_in[45]; const int* p0up=(const int*)d_in[46];
  const int* p1fp=(const int*)d_in[47]; const int* p1up=(const int*)d_in[48];
  float* out = (float*)d_out;

  float* W = (float*)d_ws;
  float* sm1 = W;                    // 110592
  float* sm2 = sm1 + 110592;         // 221184
  float* sm  = sm2 + 221184;         // 6144
  float* F0  = sm + 6144;            // 1984
  float* U0  = F0 + 1984;            // 77824
  float* F1  = U0 + 77824;           // 1984
  float* U1  = F1 + 1984;            // 77824
  // bf16 buffers (keep 16B alignment: float offsets multiple of 4)
  ushort* q16 = (ushort*)(U1 + 77824);            // 2*SEQ*32 ushorts
  ushort* k16 = q16 + 2*SEQ*32;
  ushort* vt16 = k16 + 2*SEQ*32;
  float* Hp  = (float*)(vt16 + 2*SEQ*32);         // 3*SEQ*64 floats
  float* aux = Hp + 3*SEQ*64;        // 3*2*SEQ*2
  float* seqA= aux + 3*2*SEQ*2;      // SEQ*32
  float* seqB= seqA + SEQ*32;        // SEQ*32
  float* vmap= seqB + SEQ*32;        // 66*256
  float* vp1 = vmap + 66*256;        // 96*64
  float* vp2 = vp1 + 96*64;          // 128*16

  // spatial path
  conv3x3_v2<14,48,48,1,4><<<108,256,0,stream>>>(board, sp_w1, sp_b1, sp_a1, sm1);
  conv3x3_v2<48,96,48,1,4><<<216,256,0,stream>>>(sm1, sp_w2, sp_b2, sp_a2, sm2);
  conv_s3_v2<<<12,256,0,stream>>>(sm2, sp_w3, sp_b3, sm);
  gather_concat<<<17,256,0,stream>>>(sm, p0f,p0u,p1f,p1u, p0fp,p0up,p1fp,p1up, F0,U0,F1,U1);
  vmap_init<<<66,256,0,stream>>>(sm, vmap);
  vmap_scatter<<<17,256,0,stream>>>(p0f,p0u,p1f,p1u, p0fp,p0up,p1fp,p1up, vmap);
  // value head
  vconv1_pool<<<192,128,0,stream>>>(vmap, v_w1, v_b1, v_a1, vp1);
  vconv2_pool<<<128,64,0,stream>>>(vp1, v_w2, v_b2, v_a2, vp2);
  vfinal<<<1,256,0,stream>>>(vp2, v_lw, v_lb, out + 70144);

  // encoder layer
  qkv_proj<<<396,256,0,stream>>>(F0,U0,F1,U1, 31,38, enc_fac_w,enc_fac_b,enc_unit_w,enc_unit_b, q16,k16,vt16);
  flash_mfma<<<dim3(66,2,KSPLIT),256,0,stream>>>(q16,k16,vt16,Hp,aux);
  outlin_enc2<<<528,256,0,stream>>>(Hp, aux, enc_lin_w, enc_lin_b, seqA);
  // extractor layer 0
  qkv_proj<<<396,256,0,stream>>>(seqA, seqA+64*32, seqA+2112*32, seqA+2176*32, 32,32,
      ext_fac_w, ext_fac_b, ext_unit_w, ext_unit_b, q16,k16,vt16);
  flash_mfma<<<dim3(66,2,KSPLIT),256,0,stream>>>(q16,k16,vt16,Hp,aux);
  outlin_ln2<<<528,256,0,stream>>>(Hp, aux, ext_lin_w, ext_lin_b, seqA, ext_ln_g, ext_ln_b, seqB);
  // extractor layer 1
  qkv_proj<<<396,256,0,stream>>>(seqB, seqB+64*32, seqB+2112*32, seqB+2176*32, 32,32,
      ext_fac_w+12288, ext_fac_b+384, ext_unit_w+12288, ext_unit_b+384, q16,k16,vt16);
  flash_mfma<<<dim3(66,2,KSPLIT),256,0,stream>>>(q16,k16,vt16,Hp,aux);
  outlin_ln2<<<528,256,0,stream>>>(Hp, aux, ext_lin_w+2048, ext_lin_b+32, seqB, ext_ln_g+32, ext_ln_b+32, seqA);

  head_mlp<<<17,256,0,stream>>>(seqA, fo_w1,fo_b1,fo_a,fo_w2,fo_b2, ro_w1,ro_b1,ro_a,ro_w2,ro_b2, out);
}

// Round 4
// 405.095 us; speedup vs baseline: 3.4273x; 1.0388x over previous
//
#include <hip/hip_runtime.h>
#include <hip/hip_bf16.h>

#define SEQ 4224
typedef unsigned int uint;
typedef unsigned short ushort;
typedef __attribute__((ext_vector_type(8))) short bf16x8;
typedef __attribute__((ext_vector_type(4))) float f32x4;

__device__ __forceinline__ float prelu_f(float x, float a){ return x > 0.f ? x : a*x; }

// scalar fp32 -> bf16 (RNE)
__device__ __forceinline__ ushort bfr(float x){
  uint u = __float_as_uint(x);
  u = (u + 0x7fffu + ((u>>16)&1u)) >> 16;
  return (ushort)u;
}
// packed pair via compiler (v_cvt_pk_bf16_f32 on gfx950)
__device__ __forceinline__ uint pkbf(float a, float b){
  __hip_bfloat162 h2 = __float22bfloat162_rn(make_float2(a,b));
  union { __hip_bfloat162 h; uint u; } cv; cv.h = h2; return cv.u;
}

// Q pre-scale: (1/sqrt(32)) * log2(e)  -> softmax done in exp2 domain
#define QSCALE 0.25505607190037247f

// ---------------- spatial convs (weights in LDS, CPT channels/thread) ----------------
template<int CIN, int COUT, int HW, int ACT, int CPT>
__global__ __launch_bounds__(256) void conv3x3_v2(const float* __restrict__ in, const float* __restrict__ w,
                          const float* __restrict__ bias, const float* __restrict__ alpha,
                          float* __restrict__ out) {
  __shared__ float Ws[CPT*CIN*9];
  __shared__ float Bs[CPT];
  const int PXB = HW*HW/256;
  int cg = blockIdx.x / PXB, pxb = blockIdx.x % PXB;
  int tid = threadIdx.x;
  for (int idx=tid; idx<CPT*CIN*9; idx+=256) Ws[idx] = w[cg*CPT*CIN*9 + idx];
  if (tid<CPT) Bs[tid] = bias[cg*CPT+tid];
  __syncthreads();
  int p = pxb*256 + tid;
  int x = p % HW, y = p / HW;
  float a = ACT ? alpha[0] : 0.f;
  float acc[CPT];
  #pragma unroll
  for (int c=0;c<CPT;++c) acc[c]=Bs[c];
  #pragma unroll 2
  for (int i=0;i<CIN;++i){
    const float* ip = in + i*HW*HW;
    float win[9];
    #pragma unroll
    for (int ky=0;ky<3;++ky){
      int yy = y+ky-1;
      #pragma unroll
      for (int kx=0;kx<3;++kx){
        int xx = x+kx-1;
        bool ok = ((unsigned)yy < (unsigned)HW) && ((unsigned)xx < (unsigned)HW);
        win[ky*3+kx] = ok ? ip[yy*HW+xx] : 0.f;
      }
    }
    #pragma unroll
    for (int c=0;c<CPT;++c){
      const float* wp = &Ws[(c*CIN+i)*9];
      #pragma unroll
      for (int k=0;k<9;++k) acc[c] += win[k]*wp[k];
    }
  }
  #pragma unroll
  for (int c=0;c<CPT;++c){
    float v = acc[c];
    if (ACT) v = prelu_f(v, a);
    out[(cg*CPT+c)*HW*HW + p] = v;
  }
}

// stride-3 valid conv 96->24 over 48x48 -> 16x16; 2 channels per block
__global__ __launch_bounds__(256) void conv_s3_v2(const float* __restrict__ in, const float* __restrict__ w,
                        const float* __restrict__ bias, float* __restrict__ out) {
  __shared__ float Ws[2*96*9];
  int cg = blockIdx.x;   // 12 blocks
  int tid = threadIdx.x;
  for (int idx=tid; idx<1728; idx+=256) Ws[idx] = w[cg*1728 + idx];
  __syncthreads();
  int x = tid&15, y = tid>>4;
  float a0 = bias[2*cg], a1 = bias[2*cg+1];
  const float* ip0 = in + y*144 + x*3;
  #pragma unroll 4
  for (int i=0;i<96;++i){
    const float* ip = ip0 + i*2304;
    float win[9];
    #pragma unroll
    for (int ky=0;ky<3;++ky)
      #pragma unroll
      for (int kx=0;kx<3;++kx) win[ky*3+kx] = ip[ky*48+kx];
    const float* w0 = &Ws[i*9];
    const float* w1 = &Ws[864 + i*9];
    #pragma unroll
    for (int k=0;k<9;++k){ a0 += win[k]*w0[k]; a1 += win[k]*w1[k]; }
  }
  out[(2*cg)*256 + y*16 + x] = a0;
  out[(2*cg+1)*256 + y*16 + x] = a1;
}

// ---------------- gather + concat entity features ----------------
__global__ __launch_bounds__(256) void gather_concat(const float* __restrict__ sm,
  const float* __restrict__ p0f, const float* __restrict__ p0u,
  const float* __restrict__ p1f, const float* __restrict__ p1u,
  const int* __restrict__ p0fp, const int* __restrict__ p0up,
  const int* __restrict__ p1fp, const int* __restrict__ p1up,
  float* __restrict__ F0, float* __restrict__ U0, float* __restrict__ F1, float* __restrict__ U1)
{
  int e = blockIdx.x*256+threadIdx.x;
  if (e>=SEQ) return;
  const float* feat; const int* pos; float* dst; int nf, n;
  if (e<64){ n=e; feat=p0f+n*7; pos=p0fp; dst=F0+n*31; nf=7; }
  else if (e<2112){ n=e-64; feat=p0u+n*14; pos=p0up; dst=U0+(size_t)n*38; nf=14; }
  else if (e<2176){ n=e-2112; feat=p1f+n*7; pos=p1fp; dst=F1+n*31; nf=7; }
  else { n=e-2176; feat=p1u+n*14; pos=p1up; dst=U1+(size_t)n*38; nf=14; }
  for (int c=0;c<nf;++c) dst[c]=feat[c];
  int px = pos[2*n], py = pos[2*n+1];
  const float* s = sm + px*16 + py;
  #pragma unroll
  for (int c=0;c<24;++c) dst[nf+c] = s[c*256];
}

// ---------------- value-map build ----------------
__global__ __launch_bounds__(256) void vmap_init(const float* __restrict__ sm, float* __restrict__ vmap){
  int t = blockIdx.x*256+threadIdx.x;
  if (t>=66*256) return;
  int c = t>>8;
  vmap[t] = (c<42)? 0.f : sm[t - 42*256];
}

__global__ __launch_bounds__(256) void vmap_scatter(
  const float* __restrict__ p0f, const float* __restrict__ p0u,
  const float* __restrict__ p1f, const float* __restrict__ p1u,
  const int* __restrict__ p0fp, const int* __restrict__ p0up,
  const int* __restrict__ p1fp, const int* __restrict__ p1up,
  float* __restrict__ vmap)
{
  int e = blockIdx.x*256+threadIdx.x;
  if (e>=SEQ) return;
  const float* feat; const int* pos; int n, ch0, C;
  if (e<2048){ n=e; feat=p1u+n*14; pos=p1up; ch0=0; C=14; }
  else if (e<2112){ n=e-2048; feat=p1f+n*7; pos=p1fp; ch0=14; C=7; }
  else if (e<4160){ n=e-2112; feat=p0u+n*14; pos=p0up; ch0=21; C=14; }
  else { n=e-4160; feat=p0f+n*7; pos=p0fp; ch0=35; C=7; }
  int off = pos[2*n]*16 + pos[2*n+1];
  for (int c=0;c<C;++c) atomicAdd(&vmap[(ch0+c)*256 + off], feat[c]);
}

// ---------------- QKV projection (fp32 compute, bf16 out; reg-blocked 2r x 4o) ----------------
__global__ __launch_bounds__(256) void qkv_proj2(const float* __restrict__ x0, const float* __restrict__ x1,
    const float* __restrict__ x2, const float* __restrict__ x3, int ind_f, int ind_u,
    const float* __restrict__ fw, const float* __restrict__ fb,
    const float* __restrict__ uw, const float* __restrict__ ub,
    ushort* __restrict__ Q16, ushort* __restrict__ K16, ushort* __restrict__ VT16){
  __shared__ float Xs[64*40];   // padded to 40 cols, zero-filled
  __shared__ float Ws[32*40];
  __shared__ float Bs[32];
  int blk = blockIdx.x;
  int chunk = blk % 66;
  int hm = blk / 66;       // 0..5 = m*2+h
  int m = hm >> 1, h = hm & 1;
  const float* xb; int ind, isfac, pl;
  if (chunk==0){ xb=x0; ind=ind_f; isfac=1; pl=0; }
  else if (chunk<=32){ xb=x1 + (size_t)(chunk-1)*64*ind_u; ind=ind_u; isfac=0; pl=0; }
  else if (chunk==33){ xb=x2; ind=ind_f; isfac=1; pl=1; }
  else { xb=x3 + (size_t)(chunk-34)*64*ind_u; ind=ind_u; isfac=0; pl=1; }
  int b0 = h*6 + pl*3 + m;
  const float* w = (isfac? fw:uw) + (size_t)b0*32*ind;
  const float* bias = (isfac? fb:ub) + b0*32;
  int tid = threadIdx.x;
  {
    int r = tid>>2, seg = tid&3;   // 4 threads per X row, 10 cols each
    const float* xr = xb + (size_t)r*ind;
    #pragma unroll
    for (int j=0;j<10;++j){
      int c = seg*10+j;
      Xs[r*40+c] = (c<ind) ? xr[c] : 0.f;
    }
    int o = tid>>3, sg = tid&7;    // 8 threads per W row, 5 cols each
    const float* wr = w + (size_t)o*ind;
    #pragma unroll
    for (int j=0;j<5;++j){
      int c = sg*5+j;
      Ws[o*40+c] = (c<ind) ? wr[c] : 0.f;
    }
    if (tid<32) Bs[tid]=bias[tid];
  }
  __syncthreads();
  int og = tid&7, rg = tid>>3;   // outputs o = og+8k, rows r = rg, rg+32
  const float4* Xs4 = (const float4*)Xs;
  const float4* Ws4 = (const float4*)Ws;
  float acc[2][4];
  #pragma unroll
  for (int k=0;k<4;++k){ float b = Bs[og+8*k]; acc[0][k]=b; acc[1][k]=b; }
  #pragma unroll
  for (int d4=0; d4<10; ++d4){
    float4 xa = Xs4[rg*10+d4];
    float4 xb2 = Xs4[(rg+32)*10+d4];
    #pragma unroll
    for (int k=0;k<4;++k){
      float4 wv = Ws4[(og+8*k)*10+d4];
      acc[0][k] += xa.x*wv.x + xa.y*wv.y + xa.z*wv.z + xa.w*wv.w;
      acc[1][k] += xb2.x*wv.x + xb2.y*wv.y + xb2.z*wv.z + xb2.w*wv.w;
    }
  }
  if (m==0){
    #pragma unroll
    for (int j=0;j<2;++j){
      int r = rg + 32*j;
      ushort* base = Q16 + ((size_t)h*SEQ + chunk*64 + r)*32;
      #pragma unroll
      for (int k=0;k<4;++k) base[og+8*k] = bfr(acc[j][k]*QSCALE);
    }
  } else if (m==1){
    #pragma unroll
    for (int j=0;j<2;++j){
      int r = rg + 32*j;
      ushort* base = K16 + ((size_t)h*SEQ + chunk*64 + r)*32;
      #pragma unroll
      for (int k=0;k<4;++k) base[og+8*k] = bfr(acc[j][k]);
    }
  } else {
    #pragma unroll
    for (int k=0;k<4;++k){
      ushort* base = VT16 + ((size_t)h*32 + og+8*k)*SEQ + chunk*64;
      #pragma unroll
      for (int j=0;j<2;++j) base[rg+32*j] = bfr(acc[j][k]);
    }
  }
}

// ---------------- MFMA flash attention (bf16 in, fp32 stats/acc, exp2 domain) ----------------
// grid (66 qb, 2 h, 6 ks); block 256 = 4 waves; wave w owns q-rows w*16..w*16+15.
#define KSPLIT 6
#define KITERS 11
__global__ __launch_bounds__(256) void flash_mfma(const ushort* __restrict__ Q16,
    const ushort* __restrict__ K16, const ushort* __restrict__ VT16,
    float* __restrict__ Hpart, float* __restrict__ aux){
  __shared__ ushort Ks[2][64][40];   // double-buffered, row stride 80B
  __shared__ ushort VTs[2][32][80];  // double-buffered, row stride 160B
  __shared__ ushort Pl[4][16][72];   // per-wave P, row stride 144B
  int qb = blockIdx.x, h = blockIdx.y, ks = blockIdx.z;
  int tid = threadIdx.x;
  int wv = tid>>6, l = tid&63, lq = l&15, g = l>>4;
  const ushort* Qh = Q16 + (size_t)h*SEQ*32;
  const ushort* Kh = K16 + (size_t)h*SEQ*32;
  const ushort* VTh = VT16 + (size_t)h*32*SEQ;

  // Q B-frag (held whole kernel): lane gives Q[q=lq][d=g*8..g*8+7]
  bf16x8 qf = *(const bf16x8*)(Qh + (size_t)(qb*64 + wv*16 + lq)*32 + g*8);

  int krow = tid>>2, kc8 = (tid&3)*8;       // K staging: 4 threads/row
  int vd = tid>>3, vk8 = (tid&7)*8;         // VT staging: 8 threads/row

  f32x4 o0 = {0.f,0.f,0.f,0.f}, o1 = {0.f,0.f,0.f,0.f};
  float mr = -1e30f, lrow = 0.f;

  int kt0 = ks*KITERS;
  // prologue: stage tile 0 into buffer 0
  bf16x8 kpre = *(const bf16x8*)(Kh + (size_t)(kt0*64 + krow)*32 + kc8);
  bf16x8 vpre = *(const bf16x8*)(VTh + (size_t)vd*SEQ + kt0*64 + vk8);
  *(bf16x8*)&Ks[0][krow][kc8] = kpre;
  *(bf16x8*)&VTs[0][vd][vk8] = vpre;

  for (int it=0; it<KITERS; ++it){
    int pb = it&1;
    if (it+1 < KITERS){
      kpre = *(const bf16x8*)(Kh + (size_t)((kt0+it+1)*64 + krow)*32 + kc8);
      vpre = *(const bf16x8*)(VTh + (size_t)vd*SEQ + (kt0+it+1)*64 + vk8);
    }
    __syncthreads();   // buf[pb] fully written; prior reads of buf[pb^1] done
    // ---- QK^T (swapped): S^T tiles; lane holds S[q=lq][k=16m+g*4+r] ----
    f32x4 z = {0.f,0.f,0.f,0.f};
    f32x4 sT[4];
    #pragma unroll
    for (int m=0;m<4;++m){
      bf16x8 kf = *(const bf16x8*)&Ks[pb][16*m + lq][g*8];
      sT[m] = __builtin_amdgcn_mfma_f32_16x16x32_bf16(kf, qf, z, 0, 0, 0);
    }
    // ---- online softmax (exp2 domain): lane has 16 k-values of row q=lq ----
    float tm = -1e30f;
    #pragma unroll
    for (int m=0;m<4;++m)
      tm = fmaxf(tm, fmaxf(fmaxf(sT[m][0],sT[m][1]), fmaxf(sT[m][2],sT[m][3])));
    tm = fmaxf(tm, __shfl_xor(tm,16));
    tm = fmaxf(tm, __shfl_xor(tm,32));
    float mnew = fmaxf(mr, tm);
    float rsc = exp2f(mr - mnew);
    float ts = 0.f;
    #pragma unroll
    for (int m=0;m<4;++m){
      #pragma unroll
      for (int r=0;r<4;++r){ float p = exp2f(sT[m][r]-mnew); sT[m][r]=p; ts+=p; }
    }
    ts += __shfl_xor(ts,16); ts += __shfl_xor(ts,32);
    lrow = lrow*rsc + ts; mr = mnew;
    // pack P -> LDS (bf16 via cvt_pk), row q=lq, k=16m+g*4+{0..3}
    #pragma unroll
    for (int m=0;m<4;++m){
      uint2 pw; pw.x = pkbf(sT[m][0],sT[m][1]); pw.y = pkbf(sT[m][2],sT[m][3]);
      *(uint2*)&Pl[wv][lq][16*m + g*4] = pw;
    }
    // rescale O: O rows are q'=(g*4+r) -> fetch rsc of q' via shfl
    float rr0 = __shfl(rsc, (g<<2)+0);
    float rr1 = __shfl(rsc, (g<<2)+1);
    float rr2 = __shfl(rsc, (g<<2)+2);
    float rr3 = __shfl(rsc, (g<<2)+3);
    o0[0]*=rr0; o0[1]*=rr1; o0[2]*=rr2; o0[3]*=rr3;
    o1[0]*=rr0; o1[1]*=rr1; o1[2]*=rr2; o1[3]*=rr3;
    // ---- PV: O(16q x 32d) += P(16x64)*V(64x32) ----
    #pragma unroll
    for (int s=0;s<2;++s){
      bf16x8 pf = *(const bf16x8*)&Pl[wv][lq][s*32 + g*8];
      bf16x8 vf0 = *(const bf16x8*)&VTs[pb][lq][s*32 + g*8];
      bf16x8 vf1 = *(const bf16x8*)&VTs[pb][lq+16][s*32 + g*8];
      o0 = __builtin_amdgcn_mfma_f32_16x16x32_bf16(pf, vf0, o0, 0, 0, 0);
      o1 = __builtin_amdgcn_mfma_f32_16x16x32_bf16(pf, vf1, o1, 0, 0, 0);
    }
    // stage next tile into other buffer (after compute; vmcnt wait auto)
    if (it+1 < KITERS){
      *(bf16x8*)&Ks[pb^1][krow][kc8] = kpre;
      *(bf16x8*)&VTs[pb^1][vd][vk8] = vpre;
    }
  }
  int qg0 = qb*64 + wv*16;
  #pragma unroll
  for (int r=0;r<4;++r){
    size_t row = (size_t)ks*SEQ + qg0 + g*4 + r;
    Hpart[row*64 + h*32 + lq]      = o0[r];
    Hpart[row*64 + h*32 + lq + 16] = o1[r];
  }
  if (g==0){
    float* ap = aux + ((size_t)(ks*2+h)*SEQ + qg0 + lq)*2;
    ap[0]=mr; ap[1]=lrow;
  }
}

// ---------------- MHA output linear with fused k-split combine (LDS-staged H) ----------------
__device__ __forceinline__ float combine_row(const float* __restrict__ Hp,
    const float* __restrict__ aux, int s, int d){
  int hh = d>>5;
  float m[KSPLIT], li[KSPLIT];
  #pragma unroll
  for (int p=0;p<KSPLIT;++p){
    const float* ap = aux + ((size_t)(p*2+hh)*SEQ + s)*2;
    m[p]=ap[0]; li[p]=ap[1];
  }
  float ms = m[0];
  #pragma unroll
  for (int p=1;p<KSPLIT;++p) ms = fmaxf(ms, m[p]);
  float den = 0.f, hv = 0.f;
  #pragma unroll
  for (int p=0;p<KSPLIT;++p){
    float w = exp2f(m[p]-ms);
    den += li[p]*w;
    hv  += Hp[(size_t)p*SEQ*64 + (size_t)s*64 + d]*w;
  }
  return hv/den;
}

__global__ __launch_bounds__(256) void outlin_enc3(const float* __restrict__ Hp,
     const float* __restrict__ aux, const float* __restrict__ lw,
     const float* __restrict__ lb, float* __restrict__ seqout){
  __shared__ float Ls[32*68];
  __shared__ float Hc[8*68];
  int tid=threadIdx.x;
  int s0 = blockIdx.x*8;
  for (int idx=tid; idx<2048; idx+=256){ int o=idx>>6, d=idx&63; Ls[o*68+d]=lw[idx]; }
  for (int idx=tid; idx<512; idx+=256){
    int sl = idx>>6, d = idx&63;
    Hc[sl*68+d] = combine_row(Hp, aux, s0+sl, d);
  }
  __syncthreads();
  int o = tid&31, sl = tid>>5;
  const float4* H4 = (const float4*)&Hc[sl*68];
  const float4* L4 = (const float4*)&Ls[o*68];
  float acc = lb[o];
  #pragma unroll
  for (int d4=0; d4<16; ++d4){
    float4 hv = H4[d4], lv = L4[d4];
    acc += hv.x*lv.x + hv.y*lv.y + hv.z*lv.z + hv.w*lv.w;
  }
  seqout[(s0+sl)*32+o]=acc;
}

__global__ __launch_bounds__(256) void outlin_ln3(const float* __restrict__ Hp,
    const float* __restrict__ aux, const float* __restrict__ lw,
    const float* __restrict__ lb, const float* __restrict__ seqin,
    const float* __restrict__ g, const float* __restrict__ b, float* __restrict__ seqout){
  __shared__ float Ls[32*68];
  __shared__ float Hc[8*68];
  int tid=threadIdx.x;
  int s0 = blockIdx.x*8;
  for (int idx=tid; idx<2048; idx+=256){ int o=idx>>6, d=idx&63; Ls[o*68+d]=lw[idx]; }
  for (int idx=tid; idx<512; idx+=256){
    int sl = idx>>6, d = idx&63;
    Hc[sl*68+d] = combine_row(Hp, aux, s0+sl, d);
  }
  __syncthreads();
  int o = tid&31, sl = tid>>5;
  const float4* H4 = (const float4*)&Hc[sl*68];
  const float4* L4 = (const float4*)&Ls[o*68];
  float acc = lb[o] + seqin[(s0+sl)*32+o];
  #pragma unroll
  for (int d4=0; d4<16; ++d4){
    float4 hv = H4[d4], lv = L4[d4];
    acc += hv.x*lv.x + hv.y*lv.y + hv.z*lv.z + hv.w*lv.w;
  }
  float sum=acc;
  #pragma unroll
  for (int off=1; off<32; off<<=1) sum += __shfl_xor(sum,off);
  float mu = sum*0.03125f;
  float dv = acc-mu;
  float vs = dv*dv;
  #pragma unroll
  for (int off=1; off<32; off<<=1) vs += __shfl_xor(vs,off);
  float rstd = rsqrtf(vs*0.03125f + 1e-5f);
  seqout[(s0+sl)*32+o] = dv*rstd*g[o] + b[o];
}

// ---------------- per-entity output heads ----------------
__global__ __launch_bounds__(256) void head_mlp(const float* __restrict__ seq,
  const float* __restrict__ fw1,const float* __restrict__ fb1,const float* __restrict__ fa,
  const float* __restrict__ fw2,const float* __restrict__ fb2,
  const float* __restrict__ rw1,const float* __restrict__ rb1,const float* __restrict__ ra,
  const float* __restrict__ rw2,const float* __restrict__ rb2,
  float* __restrict__ out)
{
  int e = blockIdx.x*256+threadIdx.x;
  if (e>=SEQ) return;
  const float *w1,*b1,*w2,*b2; float a; int od; float* dst;
  if (e<64){ w1=fw1;b1=fb1;a=fa[0];w2=fw2;b2=fb2;od=4; dst=out + e*4; }
  else if (e<2112){ w1=rw1;b1=rb1;a=ra[0];w2=rw2;b2=rb2;od=17; dst=out + 256 + (size_t)(e-64)*17; }
  else if (e<2176){ w1=fw1;b1=fb1;a=fa[0];w2=fw2;b2=fb2;od=4; dst=out + 35072 + (e-2112)*4; }
  else { w1=rw1;b1=rb1;a=ra[0];w2=rw2;b2=rb2;od=17; dst=out + 35328 + (size_t)(e-2176)*17; }
  float x[32];
  #pragma unroll
  for (int i=0;i<32;++i) x[i]=seq[(size_t)e*32+i];
  float hbuf[32];
  #pragma unroll
  for (int j=0;j<32;++j){
    float acc=b1[j];
    #pragma unroll
    for (int i=0;i<32;++i) acc+=w1[j*32+i]*x[i];
    hbuf[j]=prelu_f(acc,a);
  }
  for (int k=0;k<od;++k){
    float acc=b2[k];
    #pragma unroll
    for (int j=0;j<32;++j) acc+=w2[k*32+j]*hbuf[j];
    dst[k]=acc;
  }
}

// ---------------- value head conv1: 66->96 @16x16, pool to 8x8 ----------------
__global__ __launch_bounds__(128) void vconv1_pool(const float* __restrict__ in, const float* __restrict__ w,
    const float* __restrict__ bias, const float* __restrict__ alpha, float* __restrict__ out){
  __shared__ float In[66*160];   // [i][r(10)][x(16)]
  __shared__ float Wc[594];
  int c = blockIdx.x >> 1, half = blockIdx.x & 1;
  int y0 = half*8;
  int tid = threadIdx.x;
  const float4* in4 = (const float4*)in;
  float4* In4 = (float4*)In;
  for (int idx4=tid; idx4<2640; idx4+=128){
    int i = idx4/40, rem = idx4 - i*40;
    int r = rem>>2, x4 = rem&3;
    int y = y0 - 1 + r;
    float4 v;
    if ((unsigned)y < 16u) v = in4[i*64 + y*4 + x4];
    else { v.x=v.y=v.z=v.w=0.f; }
    In4[idx4] = v;
  }
  for (int idx=tid; idx<594; idx+=128) Wc[idx] = w[c*594 + idx];
  __syncthreads();
  int x = tid & 15, ry = tid >> 4;
  float a = alpha[0];
  float acc = bias[c];
  for (int i=0;i<66;++i){
    const float* base = &In[i*160 + ry*16];
    const float* wp = &Wc[i*9];
    #pragma unroll
    for (int ky=0;ky<3;++ky){
      const float* row = base + ky*16;
      #pragma unroll
      for (int kx=0;kx<3;++kx){
        int xx = x+kx-1;
        float v = ((unsigned)xx<16u) ? row[xx] : 0.f;
        acc += v*wp[ky*3+kx];
      }
    }
  }
  acc = prelu_f(acc, a);
  float mx = fmaxf(acc, __shfl_xor(acc,1));
  mx = fmaxf(mx, __shfl_xor(mx,16));
  if (((x&1)==0) && ((ry&1)==0))
    out[c*64 + (half*4 + (ry>>1))*8 + (x>>1)] = mx;
}

// ---------------- value head conv2: 96->128 @8x8, pool to 4x4 ----------------
__global__ __launch_bounds__(64) void vconv2_pool(const float* __restrict__ in, const float* __restrict__ w,
    const float* __restrict__ bias, const float* __restrict__ alpha, float* __restrict__ out){
  __shared__ float In[96*64];
  __shared__ float Ws[864];
  int c = blockIdx.x;
  int tid = threadIdx.x;
  const float4* in4 = (const float4*)in;
  float4* In4 = (float4*)In;
  for (int idx4=tid; idx4<1536; idx4+=64) In4[idx4] = in4[idx4];
  for (int idx=tid; idx<864; idx+=64) Ws[idx] = w[c*864 + idx];
  __syncthreads();
  int x = tid&7, y = tid>>3;
  float acc = bias[c];
  for (int i=0;i<96;++i){
    const float* base = &In[i*64];
    const float* wp = &Ws[i*9];
    #pragma unroll
    for (int ky=0;ky<3;++ky){
      int yy = y+ky-1;
      #pragma unroll
      for (int kx=0;kx<3;++kx){
        int xx = x+kx-1;
        bool ok = ((unsigned)yy<8u) && ((unsigned)xx<8u);
        float v = ok ? base[yy*8+xx] : 0.f;
        acc += v*wp[ky*3+kx];
      }
    }
  }
  acc = prelu_f(acc, alpha[0]);
  float mx = fmaxf(acc, __shfl_xor(acc,1));
  mx = fmaxf(mx, __shfl_xor(mx,8));
  if (((x&1)==0) && ((y&1)==0))
    out[c*16 + (y>>1)*4 + (x>>1)] = mx;
}

__global__ __launch_bounds__(256) void vfinal(const float* __restrict__ vp2, const float* __restrict__ lw,
                       const float* __restrict__ lb, float* __restrict__ outv){
  __shared__ float red[256];
  int tid=threadIdx.x;
  float s=0.f;
  for (int i=tid;i<2048;i+=256) s += vp2[i]*lw[i];
  red[tid]=s; __syncthreads();
  for (int k=128;k>0;k>>=1){ if (tid<k) red[tid]+=red[tid+k]; __syncthreads(); }
  if (tid==0) outv[0] = tanhf(red[0]+lb[0]);
}

// ---------------- host ----------------
extern "C" void kernel_launch(void* const* d_in, const int* in_sizes, int n_in,
                              void* d_out, int out_size, void* d_ws, size_t ws_size,
                              hipStream_t stream){
  (void)in_sizes; (void)n_in; (void)out_size; (void)ws_size;
  const float* board = (const float*)d_in[0];
  const float* p0f = (const float*)d_in[1];
  const float* p0u = (const float*)d_in[2];
  const float* p1f = (const float*)d_in[3];
  const float* p1u = (const float*)d_in[4];
  const float* sp_w1=(const float*)d_in[5];  const float* sp_b1=(const float*)d_in[6];  const float* sp_a1=(const float*)d_in[7];
  const float* sp_w2=(const float*)d_in[8];  const float* sp_b2=(const float*)d_in[9];  const float* sp_a2=(const float*)d_in[10];
  const float* sp_w3=(const float*)d_in[11]; const float* sp_b3=(const float*)d_in[12];
  const float* enc_fac_w=(const float*)d_in[13]; const float* enc_fac_b=(const float*)d_in[14];
  const float* enc_unit_w=(const float*)d_in[15]; const float* enc_unit_b=(const float*)d_in[16];
  const float* enc_lin_w=(const float*)d_in[17]; const float* enc_lin_b=(const float*)d_in[18];
  const float* ext_fac_w=(const float*)d_in[19]; const float* ext_fac_b=(const float*)d_in[20];
  const float* ext_unit_w=(const float*)d_in[21]; const float* ext_unit_b=(const float*)d_in[22];
  const float* ext_lin_w=(const float*)d_in[23]; const float* ext_lin_b=(const float*)d_in[24];
  const float* ext_ln_g=(const float*)d_in[25]; const float* ext_ln_b=(const float*)d_in[26];
  const float* v_w1=(const float*)d_in[27]; const float* v_b1=(const float*)d_in[28]; const float* v_a1=(const float*)d_in[29];
  const float* v_w2=(const float*)d_in[30]; const float* v_b2=(const float*)d_in[31]; const float* v_a2=(const float*)d_in[32];
  const float* v_lw=(const float*)d_in[33]; const float* v_lb=(const float*)d_in[34];
  const float* fo_w1=(const float*)d_in[35]; const float* fo_b1=(const float*)d_in[36]; const float* fo_a=(const float*)d_in[37];
  const float* fo_w2=(const float*)d_in[38]; const float* fo_b2=(const float*)d_in[39];
  const float* ro_w1=(const float*)d_in[40]; const float* ro_b1=(const float*)d_in[41]; const float* ro_a=(const float*)d_in[42];
  const float* ro_w2=(const float*)d_in[43]; const float* ro_b2=(const float*)d_in[44];
  const int* p0fp=(const int*)d_in[45]; const int* p0up=(const int*)d_in[46];
  const int* p1fp=(const int*)d_in[47]; const int* p1up=(const int*)d_in[48];
  float* out = (float*)d_out;

  float* W = (float*)d_ws;
  float* sm1 = W;                    // 110592
  float* sm2 = sm1 + 110592;         // 221184
  float* sm  = sm2 + 221184;         // 6144
  float* F0  = sm + 6144;            // 1984
  float* U0  = F0 + 1984;            // 77824
  float* F1  = U0 + 77824;           // 1984
  float* U1  = F1 + 1984;            // 77824
  ushort* q16 = (ushort*)(U1 + 77824);            // 2*SEQ*32 ushorts each
  ushort* k16 = q16 + 2*SEQ*32;
  ushort* vt16 = k16 + 2*SEQ*32;
  float* Hp  = (float*)(vt16 + 2*SEQ*32);         // KSPLIT*SEQ*64 floats
  float* aux = Hp + KSPLIT*SEQ*64;   // KSPLIT*2*SEQ*2
  float* seqA= aux + KSPLIT*2*SEQ*2; // SEQ*32
  float* seqB= seqA + SEQ*32;        // SEQ*32
  float* vmap= seqB + SEQ*32;        // 66*256
  float* vp1 = vmap + 66*256;        // 96*64
  float* vp2 = vp1 + 96*64;          // 128*16

  // spatial path
  conv3x3_v2<14,48,48,1,4><<<108,256,0,stream>>>(board, sp_w1, sp_b1, sp_a1, sm1);
  conv3x3_v2<48,96,48,1,4><<<216,256,0,stream>>>(sm1, sp_w2, sp_b2, sp_a2, sm2);
  conv_s3_v2<<<12,256,0,stream>>>(sm2, sp_w3, sp_b3, sm);
  gather_concat<<<17,256,0,stream>>>(sm, p0f,p0u,p1f,p1u, p0fp,p0up,p1fp,p1up, F0,U0,F1,U1);
  vmap_init<<<66,256,0,stream>>>(sm, vmap);
  vmap_scatter<<<17,256,0,stream>>>(p0f,p0u,p1f,p1u, p0fp,p0up,p1fp,p1up, vmap);
  // value head
  vconv1_pool<<<192,128,0,stream>>>(vmap, v_w1, v_b1, v_a1, vp1);
  vconv2_pool<<<128,64,0,stream>>>(vp1, v_w2, v_b2, v_a2, vp2);
  vfinal<<<1,256,0,stream>>>(vp2, v_lw, v_lb, out + 70144);

  // encoder layer
  qkv_proj2<<<396,256,0,stream>>>(F0,U0,F1,U1, 31,38, enc_fac_w,enc_fac_b,enc_unit_w,enc_unit_b, q16,k16,vt16);
  flash_mfma<<<dim3(66,2,KSPLIT),256,0,stream>>>(q16,k16,vt16,Hp,aux);
  outlin_enc3<<<528,256,0,stream>>>(Hp, aux, enc_lin_w, enc_lin_b, seqA);
  // extractor layer 0
  qkv_proj2<<<396,256,0,stream>>>(seqA, seqA+64*32, seqA+2112*32, seqA+2176*32, 32,32,
      ext_fac_w, ext_fac_b, ext_unit_w, ext_unit_b, q16,k16,vt16);
  flash_mfma<<<dim3(66,2,KSPLIT),256,0,stream>>>(q16,k16,vt16,Hp,aux);
  outlin_ln3<<<528,256,0,stream>>>(Hp, aux, ext_lin_w, ext_lin_b, seqA, ext_ln_g, ext_ln_b, seqB);
  // extractor layer 1
  qkv_proj2<<<396,256,0,stream>>>(seqB, seqB+64*32, seqB+2112*32, seqB+2176*32, 32,32,
      ext_fac_w+12288, ext_fac_b+384, ext_unit_w+12288, ext_unit_b+384, q16,k16,vt16);
  flash_mfma<<<dim3(66,2,KSPLIT),256,0,stream>>>(q16,k16,vt16,Hp,aux);
  outlin_ln3<<<528,256,0,stream>>>(Hp, aux, ext_lin_w+2048, ext_lin_b+32, seqB, ext_ln_g+32, ext_ln_b+32, seqA);

  head_mlp<<<17,256,0,stream>>>(seqA, fo_w1,fo_b1,fo_a,fo_w2,fo_b2, ro_w1,ro_b1,ro_a,ro_w2,ro_b2, out);
}